// Round 14
// baseline (754.367 us; speedup 1.0000x reference)
//
#include <hip/hip_runtime.h>
#include <math.h>

// GLIFR (BNNFC) : B=32, T=1000, IN=256, H=512, OUT=128, A=2, DELAY=20
//  R14 = ABLATION ROUND. phase2 templated: V0 full (real), V1 no-GEMM,
//  V2 no-serial-ew, V3 no-F3-store. Dummies run 26 stages into scratch;
//  rocprof per-dispatch durations decompose the ~6.6us/stage wall that
//  survived R7-R13 (W-residency x5, ff-syn LDS path).
//  V0 change vs R13: HW fp8 convert (cvt_pk_fp8_f32) replaces sw f2e4m3.

constexpr int Bsz   = 32;
constexpr int Tn    = 1000;
constexpr int INn   = 256;
constexpr int Hn    = 512;
constexpr int OUTn  = 128;
constexpr int DELAY = 20;
constexpr int NBLK  = Tn / DELAY;   // 50
constexpr float DTc = 0.05f;
constexpr float Rc  = 0.1f;
constexpr int BH = Bsz * Hn;                  // 16384

typedef __attribute__((ext_vector_type(8))) short short8v;  // 8 bf16
typedef __attribute__((ext_vector_type(4))) float f32x4;

__device__ __forceinline__ float sigmoidf_(float x) {
    return 1.0f / (1.0f + expf(-x));
}
__device__ __forceinline__ float sigfast_(float x) {
    return __builtin_amdgcn_rcpf(1.0f + __builtin_amdgcn_exp2f(x * -1.44269504f));
}
__device__ __forceinline__ float bf2f(unsigned short u) {
    return __uint_as_float(((unsigned)u) << 16);
}
__device__ __forceinline__ unsigned short f2bf(float f) {
    unsigned x = __float_as_uint(f);
    return (unsigned short)((x + 0x7fff + ((x >> 16) & 1)) >> 16);  // RNE
}
// OCP e4m3fn encode: HW packed convert if available, else sw RNE
__device__ __forceinline__ unsigned char f2e4m3(float x) {
#if __has_builtin(__builtin_amdgcn_cvt_pk_fp8_f32)
    return (unsigned char)(__builtin_amdgcn_cvt_pk_fp8_f32(x, 0.f, 0, false) & 0xff);
#else
    unsigned b = __float_as_uint(x);
    unsigned s = (b >> 31) << 7;
    b &= 0x7fffffffu;
    unsigned code;
    if (__uint_as_float(b) < 0.015625f) {
        code = (unsigned)__float2int_rn(__uint_as_float(b) * 512.0f);
    } else {
        unsigned r = b + 0x7ffffu + ((b >> 20) & 1);
        int e = (int)(r >> 23) - 127;
        code = (unsigned)(((e + 7) << 3) | ((r >> 20) & 7));
    }
    return (unsigned char)(s | code);
#endif
}
__device__ __forceinline__ void gl_lds16(const void* g, void* l) {
    __builtin_amdgcn_global_load_lds(
        (const __attribute__((address_space(1))) void*)g,
        (__attribute__((address_space(3))) void*)l, 16, 0, 0);
}

// ---------------------------------------------------------------------------
// input [B,T,IN] fp32 -> Abf blocked bf16 [mtile 250][kt 4][kq 8][row 128][e 8]
// ---------------------------------------------------------------------------
__global__ __launch_bounds__(256) void cvt_in(
    const float* __restrict__ in, unsigned short* __restrict__ Abf)
{
    __shared__ float t[128][65];
    const int tid = threadIdx.x;
    const int mtile = blockIdx.x >> 2, kt = blockIdx.x & 3;
    const int rr = tid >> 4, cc = (tid & 15) * 4;
#pragma unroll
    for (int j = 0; j < 8; ++j) {
        int row = j * 16 + rr;
        int m = mtile * 128 + row;
        float4 v = *(const float4*)
            &in[((long)(m & 31) * Tn + (m >> 5)) * INn + kt * 64 + cc];
        t[row][cc] = v.x; t[row][cc + 1] = v.y;
        t[row][cc + 2] = v.z; t[row][cc + 3] = v.w;
    }
    __syncthreads();
    unsigned short* dst = Abf + (long)(mtile * 4 + kt) * 8192;
#pragma unroll
    for (int j = 0; j < 4; ++j) {
        int q = tid + 256 * j;
        int kq = q >> 7, row = q & 127;
        short8v o;
#pragma unroll
        for (int i = 0; i < 8; ++i) o[i] = (short)f2bf(t[row][kq * 8 + i]);
        *(short8v*)&dst[(long)q * 8] = o;
    }
}

// ---------------------------------------------------------------------------
// Weight [K][NG] fp32 -> blocked bf16 B^T tiles [ntile][KT_][kq 8][n 64][e 8]
// ---------------------------------------------------------------------------
template<int KT_, int NG>
__global__ __launch_bounds__(256) void cvt_b(
    const float* __restrict__ Wg, unsigned short* __restrict__ Bb)
{
    int c = blockIdx.x * 256 + threadIdx.x;
    int n = c & 63;
    int c2 = c >> 6;
    int kq = c2 & 7;
    int c3 = c2 >> 3;
    int kt = c3 % KT_, ntile = c3 / KT_;
    short8v o;
#pragma unroll
    for (int i = 0; i < 8; ++i)
        o[i] = (short)f2bf(Wg[(long)(kt * 64 + kq * 8 + i) * NG + ntile * 64 + n]);
    *(short8v*)&Bb[(long)c * 8] = o;
}

// ---------------------------------------------------------------------------
// W_lat [k][h] fp32 -> Wq [h][k] fp8 e4m3 (transposed), 32x32 LDS tiles
// ---------------------------------------------------------------------------
__global__ __launch_bounds__(256) void wlat_cvt(
    const float* __restrict__ W, unsigned char* __restrict__ Wq)
{
    __shared__ float tile[32][33];
    const int tid = threadIdx.x;
    const int bx = blockIdx.x & 15, by = blockIdx.x >> 4;
    const int x = tid & 31, y = tid >> 5;
#pragma unroll
    for (int j = 0; j < 4; ++j)
        tile[y + j * 8][x] = W[(long)(by * 32 + y + j * 8) * Hn + bx * 32 + x];
    __syncthreads();
#pragma unroll
    for (int j = 0; j < 4; ++j)
        Wq[(long)(bx * 32 + y + j * 8) * Hn + by * 32 + x] =
            f2e4m3(tile[x][y + j * 8]);
}

// ---------------------------------------------------------------------------
// bf16 MFMA GEMM: 128x64 tile, BK=64, 256 thr (4 waves). (ph1/ph3)
// ---------------------------------------------------------------------------
template<int KT, bool OUT_BT, bool BIAS, bool CBF16>
__global__ __launch_bounds__(256) void gemm_mfma(
    const unsigned short* __restrict__ A, const unsigned short* __restrict__ Bm,
    void* __restrict__ Cv, const float* __restrict__ bias, int N)
{
    __shared__ unsigned short Asl[2][8192];
    __shared__ unsigned short Bsl[2][4096];

    const int tid = threadIdx.x, lane = tid & 63, w = tid >> 6;
    const int ntile = blockIdx.x, mtile = blockIdx.y;
    const unsigned short* Abase = A + (long)mtile * KT * 8192;
    const unsigned short* Bbase = Bm + (long)ntile * KT * 4096;

    auto stageA = [&](int kt, int buf) {
#pragma unroll
        for (int j = 0; j < 4; ++j) {
            int c = tid + 256 * j;
            gl_lds16(Abase + (long)kt * 8192 + (long)c * 8, &Asl[buf][c * 8]);
        }
    };
    auto stageB = [&](int kt, int buf) {
#pragma unroll
        for (int j = 0; j < 2; ++j) {
            int c = tid + 256 * j;
            gl_lds16(Bbase + (long)kt * 4096 + (long)c * 8, &Bsl[buf][c * 8]);
        }
    };

    f32x4 acc[2][4] = {};
    stageA(0, 0); stageB(0, 0);
    int cur = 0;
#pragma unroll
    for (int kt = 0; kt < KT; ++kt) {
        __syncthreads();
        if (kt + 1 < KT) { stageA(kt + 1, cur ^ 1); stageB(kt + 1, cur ^ 1); }
#pragma unroll
        for (int ks = 0; ks < 2; ++ks) {
            const int kq = ks * 4 + (lane >> 4);
            short8v bfr[4];
#pragma unroll
            for (int nt = 0; nt < 4; ++nt)
                bfr[nt] = *(const short8v*)
                    &Bsl[cur][kq * 512 + (nt * 16 + (lane & 15)) * 8];
#pragma unroll
            for (int mt = 0; mt < 2; ++mt) {
                short8v afr = *(const short8v*)
                    &Asl[cur][kq * 1024 + (w * 32 + mt * 16 + (lane & 15)) * 8];
#pragma unroll
                for (int nt = 0; nt < 4; ++nt)
                    acc[mt][nt] = __builtin_amdgcn_mfma_f32_16x16x32_bf16(
                        afr, bfr[nt], acc[mt][nt], 0, 0, 0);
            }
        }
        cur ^= 1;
    }
#pragma unroll
    for (int mt = 0; mt < 2; ++mt)
#pragma unroll
        for (int r = 0; r < 4; ++r) {
            int row = mtile * 128 + w * 32 + mt * 16 + (lane >> 4) * 4 + r;
            long crow = OUT_BT ? ((long)(row & 31) * Tn + (row >> 5)) * N
                               : (long)row * N;
#pragma unroll
            for (int nt = 0; nt < 4; ++nt) {
                int col = ntile * 64 + nt * 16 + (lane & 15);
                float v = acc[mt][nt][r];
                if (BIAS) v += bias[col];
                if (CBF16) ((unsigned short*)Cv)[crow + col] = f2bf(v);
                else       ((float*)Cv)[crow + col] = v;
            }
        }
}

// ---------------------------------------------------------------------------
// Phase 2 template. V=0 full, V=1 no-GEMM, V=2 no-serial-ew, V=3 no-F3.
// Structure identical to R13 (SynL LDS ff path, W wreg as in R9).
// ---------------------------------------------------------------------------
template<int V, int NB>
__global__ __launch_bounds__(512) void phase2_var(
    const unsigned char* __restrict__ Wq,
    const unsigned short* __restrict__ SYN,
    unsigned short* __restrict__ F3,
    const float* __restrict__ tkm, const float* __restrict__ thr,
    const float* __restrict__ aamp, const float* __restrict__ tascr,
    const float* __restrict__ tkasc)
{
    __shared__ unsigned char A_lds[2][32 * 512];
    __shared__ unsigned short Sy[DELAY][520];
    __shared__ unsigned short SynL[2][DELAY][512];

    const int tid = threadIdx.x;
    const int b = blockIdx.x;
    const int lane = tid & 63, w = tid >> 6;

#pragma unroll
    for (int j = 0; j < 4; ++j)
        *(uint4*)(&A_lds[0][0] + (j * 512 + tid) * 16) = make_uint4(0u,0u,0u,0u);
    if (V == 1) {   // Sy never written by GEMM in V1: zero it once
#pragma unroll
        for (int j = 0; j < 3; ++j) {
            int q = j * 512 + tid;
            if (q < 1300) ((uint2*)&Sy[0][0])[q] = make_uint2(0u, 0u);
        }
    }

    long long wreg[16][4];
    if (V != 1) {
#pragma unroll
        for (int kt = 0; kt < 16; ++kt)
#pragma unroll
            for (int nt = 0; nt < 4; ++nt) {
                int n = w * 64 + nt * 16 + (lane & 15);
                int kk = kt * 32 + (lane >> 4) * 8;
                wreg[kt][nt] = *(const long long*)&Wq[(long)n * Hn + kk];
            }
    }

    const int h = tid;
    const float dkm  = sigmoidf_(tkm[h]);
    const float th   = thr[h];
    const float am0  = aamp[h],       am1 = aamp[Hn + h];
    const float rr0  = 1.f - 2.f * sigmoidf_(tascr[h]);
    const float rr1  = 1.f - 2.f * sigmoidf_(tascr[Hn + h]);
    const float dk0  = sigmoidf_(tkasc[h]);
    const float dk1  = sigmoidf_(tkasc[Hn + h]);
    const float kR   = dkm * Rc;
    float volt = 0.f, fir = 0.f, a0 = 0.f, a1 = 0.f;

    const long f3_h = ((long)(h >> 6) * 8 + ((h >> 3) & 7)) * 1024 + (h & 7);

    const int ar0 = lane & 15, ar1 = 16 + (lane & 15);
    const unsigned a0base = (unsigned)(ar0 * 512 + (lane >> 4) * 8);
    const unsigned a1base = (unsigned)(ar1 * 512 + (lane >> 4) * 8);
    const unsigned swz0 = (unsigned)((ar0 & 7) << 3);
    const unsigned swz1 = (unsigned)((ar1 & 7) << 3);

    auto prefetchSyn = [&](int k2) {
        const int buf = k2 & 1;
        const unsigned short* base = SYN + (long)k2 * DELAY * BH + (long)b * Hn
                                     + lane * 8;
        int r0 = w * 2;
        gl_lds16(base + (long)r0 * BH,       &SynL[buf][r0][0]);
        gl_lds16(base + (long)(r0 + 1) * BH, &SynL[buf][r0 + 1][0]);
        if (w < 4)
            gl_lds16(base + (long)(16 + w) * BH, &SynL[buf][16 + w][0]);
    };

    prefetchSyn(0);
    __syncthreads();

#pragma unroll 1
    for (int k = 0; k < NB; ++k) {
        if (k + 1 < NB) prefetchSyn(k + 1);

        if (V != 1 && k > 0) {
            const unsigned char* Ab = &A_lds[k & 1][0];
            f32x4 acc[2][4] = {};
#pragma unroll
            for (int kt = 0; kt < 16; ++kt) {
                long long afr0 = *(const long long*)(Ab + ((a0base + kt * 32) ^ swz0));
                long long afr1 = *(const long long*)(Ab + ((a1base + kt * 32) ^ swz1));
#pragma unroll
                for (int nt = 0; nt < 4; ++nt) {
                    acc[0][nt] = __builtin_amdgcn_mfma_f32_16x16x32_fp8_fp8(
                        afr0, wreg[kt][nt], acc[0][nt], 0, 0, 0);
                    acc[1][nt] = __builtin_amdgcn_mfma_f32_16x16x32_fp8_fp8(
                        afr1, wreg[kt][nt], acc[1][nt], 0, 0, 0);
                }
            }
#pragma unroll
            for (int mt = 0; mt < 2; ++mt)
#pragma unroll
                for (int r = 0; r < 4; ++r) {
                    int row = mt * 16 + (lane >> 4) * 4 + r;
                    if (row < DELAY) {
#pragma unroll
                        for (int nt = 0; nt < 4; ++nt)
                            Sy[row][w * 64 + nt * 16 + (lane & 15)]
                                = f2bf(acc[mt][nt][r]);
                    }
                }
        }

        unsigned char* An = &A_lds[(k + 1) & 1][0];
        const int mbase = k * DELAY * Bsz + b;
        const unsigned short* SynR = &SynL[k & 1][0][0];
#pragma unroll
        for (int s = 0; s < DELAY; ++s) {
            float sv = bf2f(SynR[s * 512 + h]);
            if (k > 0) sv += bf2f(Sy[s][h]);
            float fv;
            if (V == 2) {
                fv = sv * 0.1f;              // load-dependent, no serial chain
            } else {
                a0 = a0 * (rr0 * fir * DTc + (1.f - dk0)) + am0 * fir * DTc;
                a1 = a1 * (rr1 * fir * DTc + (1.f - dk1)) + am1 * fir * DTc;
                volt = volt * (1.f - dkm - fir) + kR * (sv + a0 + a1);
                fir = sigfast_(volt - th);
                fv = fir;
            }
            An[(unsigned)(s * 512 + h) ^ ((unsigned)(s & 7) << 3)] = f2e4m3(fv);
            if (V != 3) {
                int m = mbase + s * Bsz;
                F3[(long)(m >> 7) * 65536 + f3_h + (long)(m & 127) * 8] = f2bf(fv);
            } else {
                asm volatile("" :: "v"(fv));
            }
        }
        __syncthreads();
    }
}

extern "C" void kernel_launch(void* const* d_in, const int* in_sizes, int n_in,
                              void* d_out, int out_size, void* d_ws, size_t ws_size,
                              hipStream_t stream) {
    const float* input = (const float*)d_in[0];   // [B,T,IN]
    const float* w_iv  = (const float*)d_in[1];   // [IN,H]
    const float* w_lat = (const float*)d_in[2];   // [H,H]
    const float* thr   = (const float*)d_in[3];   // [1,H]
    const float* tkm   = (const float*)d_in[4];   // [1,H]
    const float* aamp  = (const float*)d_in[5];   // [A,1,H]
    const float* tascr = (const float*)d_in[6];   // [A,1,H]
    const float* tkasc = (const float*)d_in[7];   // [A,1,H]
    const float* outw  = (const float*)d_in[8];   // [H,OUT]
    const float* outb  = (const float*)d_in[9];   // [OUT]
    float* out = (float*)d_out;                   // [B,T,OUT]

    const size_t TBH = (size_t)Tn * BH;           // 16,384,000
    unsigned short* SYNb = (unsigned short*)d_ws;         // [T][B][H] bf16
    unsigned short* F3   = SYNb + TBH;                    // blocked bf16 F
    unsigned short* F3d  = F3 + TBH;                      // ablation scratch
    unsigned short* Abf  = F3d + TBH;                     // blocked bf16 input
    unsigned char* Wq    = (unsigned char*)(Abf + (size_t)8192 * 1000);
    unsigned short* Wivb = (unsigned short*)(Wq + (size_t)Hn * Hn);
    unsigned short* Wowb = Wivb + (size_t)INn * Hn;

    // Phase 0: conversions
    cvt_in<<<1000, 256, 0, stream>>>(input, Abf);
    cvt_b<4, 512><<<64, 256, 0, stream>>>(w_iv, Wivb);
    cvt_b<8, 128><<<32, 256, 0, stream>>>(outw, Wowb);
    wlat_cvt<<<256, 256, 0, stream>>>(w_lat, Wq);

    // Phase 1: SYN(bf16) = input @ W_iv
    gemm_mfma<4, false, false, true><<<dim3(8, 250), 256, 0, stream>>>(
        Abf, Wivb, SYNb, nullptr, Hn);

    // ---- ABLATION dispatches (26 stages each, scratch output) ----
    phase2_var<1, 26><<<32, 512, 0, stream>>>(Wq, SYNb, F3d,
                                              tkm, thr, aamp, tascr, tkasc);
    phase2_var<2, 26><<<32, 512, 0, stream>>>(Wq, SYNb, F3d,
                                              tkm, thr, aamp, tascr, tkasc);
    phase2_var<3, 26><<<32, 512, 0, stream>>>(Wq, SYNb, F3d,
                                              tkm, thr, aamp, tascr, tkasc);

    // Phase 2 (real): full 50 stages
    phase2_var<0, NBLK><<<32, 512, 0, stream>>>(Wq, SYNb, F3,
                                                tkm, thr, aamp, tascr, tkasc);

    // Phase 3: out = F @ out_w + out_b
    gemm_mfma<8, true, true, false><<<dim3(2, 250), 256, 0, stream>>>(
        F3, Wowb, out, outb, OUTn);
}

// Round 15
// 285.647 us; speedup vs baseline: 2.6409x; 2.6409x over previous
//
#include <hip/hip_runtime.h>
#include <math.h>

// GLIFR (BNNFC) : B=32, T=1000, IN=256, H=512, OUT=128, A=2, DELAY=20
//  cvts: input->Abf (blocked bf16), W_iv/out_w -> blocked bf16, W_lat -> fp8
//  ph1: SYN(bf16 flat [t][b][h]) = input @ W_iv   (bf16 MFMA GEMM)
//  ph2: 32 blocks (one batch each), 512 thr. R15: F stored FLAT bf16
//       ([t*32+b][h] -> coalesced 1KB bursts; old blocked layout had ~8x
//       cacheline write amplification, ~1.2us/stage). Sy transposed [h][24]
//       (vector ds_read instead of 20 scalar u16). ff in regs. W as R9.
//  ph3: out = F_flat @ out_w + out_b  (bf16 MFMA GEMM, pre-swizzled A stage)

constexpr int Bsz   = 32;
constexpr int Tn    = 1000;
constexpr int INn   = 256;
constexpr int Hn    = 512;
constexpr int OUTn  = 128;
constexpr int DELAY = 20;
constexpr int NBLK  = Tn / DELAY;   // 50
constexpr float DTc = 0.05f;
constexpr float Rc  = 0.1f;
constexpr int BH = Bsz * Hn;                  // 16384

typedef __attribute__((ext_vector_type(8))) short short8v;  // 8 bf16
typedef __attribute__((ext_vector_type(4))) float f32x4;

__device__ __forceinline__ float sigmoidf_(float x) {
    return 1.0f / (1.0f + expf(-x));
}
__device__ __forceinline__ float sigfast_(float x) {
    return __builtin_amdgcn_rcpf(1.0f + __builtin_amdgcn_exp2f(x * -1.44269504f));
}
__device__ __forceinline__ float bf2f(unsigned short u) {
    return __uint_as_float(((unsigned)u) << 16);
}
__device__ __forceinline__ unsigned short f2bf(float f) {
    unsigned x = __float_as_uint(f);
    return (unsigned short)((x + 0x7fff + ((x >> 16) & 1)) >> 16);  // RNE
}
// OCP e4m3fn encode: HW packed convert if available, else sw RNE
__device__ __forceinline__ unsigned char f2e4m3(float x) {
#if __has_builtin(__builtin_amdgcn_cvt_pk_fp8_f32)
    return (unsigned char)(__builtin_amdgcn_cvt_pk_fp8_f32(x, 0.f, 0, false) & 0xff);
#else
    unsigned b = __float_as_uint(x);
    unsigned s = (b >> 31) << 7;
    b &= 0x7fffffffu;
    unsigned code;
    if (__uint_as_float(b) < 0.015625f) {
        code = (unsigned)__float2int_rn(__uint_as_float(b) * 512.0f);
    } else {
        unsigned r = b + 0x7ffffu + ((b >> 20) & 1);
        int e = (int)(r >> 23) - 127;
        code = (unsigned)(((e + 7) << 3) | ((r >> 20) & 7));
    }
    return (unsigned char)(s | code);
#endif
}
__device__ __forceinline__ void gl_lds16(const void* g, void* l) {
    __builtin_amdgcn_global_load_lds(
        (const __attribute__((address_space(1))) void*)g,
        (__attribute__((address_space(3))) void*)l, 16, 0, 0);
}

// ---------------------------------------------------------------------------
// input [B,T,IN] fp32 -> Abf blocked bf16 [mtile 250][kt 4][kq 8][row 128][e 8]
// ---------------------------------------------------------------------------
__global__ __launch_bounds__(256) void cvt_in(
    const float* __restrict__ in, unsigned short* __restrict__ Abf)
{
    __shared__ float t[128][65];
    const int tid = threadIdx.x;
    const int mtile = blockIdx.x >> 2, kt = blockIdx.x & 3;
    const int rr = tid >> 4, cc = (tid & 15) * 4;
#pragma unroll
    for (int j = 0; j < 8; ++j) {
        int row = j * 16 + rr;
        int m = mtile * 128 + row;
        float4 v = *(const float4*)
            &in[((long)(m & 31) * Tn + (m >> 5)) * INn + kt * 64 + cc];
        t[row][cc] = v.x; t[row][cc + 1] = v.y;
        t[row][cc + 2] = v.z; t[row][cc + 3] = v.w;
    }
    __syncthreads();
    unsigned short* dst = Abf + (long)(mtile * 4 + kt) * 8192;
#pragma unroll
    for (int j = 0; j < 4; ++j) {
        int q = tid + 256 * j;
        int kq = q >> 7, row = q & 127;
        short8v o;
#pragma unroll
        for (int i = 0; i < 8; ++i) o[i] = (short)f2bf(t[row][kq * 8 + i]);
        *(short8v*)&dst[(long)q * 8] = o;
    }
}

// ---------------------------------------------------------------------------
// Weight [K][NG] fp32 -> blocked bf16 B^T tiles [ntile][KT_][kq 8][n 64][e 8]
// ---------------------------------------------------------------------------
template<int KT_, int NG>
__global__ __launch_bounds__(256) void cvt_b(
    const float* __restrict__ Wg, unsigned short* __restrict__ Bb)
{
    int c = blockIdx.x * 256 + threadIdx.x;
    int n = c & 63;
    int c2 = c >> 6;
    int kq = c2 & 7;
    int c3 = c2 >> 3;
    int kt = c3 % KT_, ntile = c3 / KT_;
    short8v o;
#pragma unroll
    for (int i = 0; i < 8; ++i)
        o[i] = (short)f2bf(Wg[(long)(kt * 64 + kq * 8 + i) * NG + ntile * 64 + n]);
    *(short8v*)&Bb[(long)c * 8] = o;
}

// ---------------------------------------------------------------------------
// W_lat [k][h] fp32 -> Wq [h][k] fp8 e4m3 (transposed), 32x32 LDS tiles
// ---------------------------------------------------------------------------
__global__ __launch_bounds__(256) void wlat_cvt(
    const float* __restrict__ W, unsigned char* __restrict__ Wq)
{
    __shared__ float tile[32][33];
    const int tid = threadIdx.x;
    const int bx = blockIdx.x & 15, by = blockIdx.x >> 4;
    const int x = tid & 31, y = tid >> 5;
#pragma unroll
    for (int j = 0; j < 4; ++j)
        tile[y + j * 8][x] = W[(long)(by * 32 + y + j * 8) * Hn + bx * 32 + x];
    __syncthreads();
#pragma unroll
    for (int j = 0; j < 4; ++j)
        Wq[(long)(bx * 32 + y + j * 8) * Hn + by * 32 + x] =
            f2e4m3(tile[x][y + j * 8]);
}

// ---------------------------------------------------------------------------
// ph1 bf16 MFMA GEMM: 128x64 tile, BK=64, 256 thr. A blocked, C bf16 flat.
// ---------------------------------------------------------------------------
template<int KT>
__global__ __launch_bounds__(256) void gemm_ph1(
    const unsigned short* __restrict__ A, const unsigned short* __restrict__ Bm,
    unsigned short* __restrict__ C, int N)
{
    __shared__ unsigned short Asl[2][8192];
    __shared__ unsigned short Bsl[2][4096];

    const int tid = threadIdx.x, lane = tid & 63, w = tid >> 6;
    const int ntile = blockIdx.x, mtile = blockIdx.y;
    const unsigned short* Abase = A + (long)mtile * KT * 8192;
    const unsigned short* Bbase = Bm + (long)ntile * KT * 4096;

    auto stageA = [&](int kt, int buf) {
#pragma unroll
        for (int j = 0; j < 4; ++j) {
            int c = tid + 256 * j;
            gl_lds16(Abase + (long)kt * 8192 + (long)c * 8, &Asl[buf][c * 8]);
        }
    };
    auto stageB = [&](int kt, int buf) {
#pragma unroll
        for (int j = 0; j < 2; ++j) {
            int c = tid + 256 * j;
            gl_lds16(Bbase + (long)kt * 4096 + (long)c * 8, &Bsl[buf][c * 8]);
        }
    };

    f32x4 acc[2][4] = {};
    stageA(0, 0); stageB(0, 0);
    int cur = 0;
#pragma unroll
    for (int kt = 0; kt < KT; ++kt) {
        __syncthreads();
        if (kt + 1 < KT) { stageA(kt + 1, cur ^ 1); stageB(kt + 1, cur ^ 1); }
#pragma unroll
        for (int ks = 0; ks < 2; ++ks) {
            const int kq = ks * 4 + (lane >> 4);
            short8v bfr[4];
#pragma unroll
            for (int nt = 0; nt < 4; ++nt)
                bfr[nt] = *(const short8v*)
                    &Bsl[cur][kq * 512 + (nt * 16 + (lane & 15)) * 8];
#pragma unroll
            for (int mt = 0; mt < 2; ++mt) {
                short8v afr = *(const short8v*)
                    &Asl[cur][kq * 1024 + (w * 32 + mt * 16 + (lane & 15)) * 8];
#pragma unroll
                for (int nt = 0; nt < 4; ++nt)
                    acc[mt][nt] = __builtin_amdgcn_mfma_f32_16x16x32_bf16(
                        afr, bfr[nt], acc[mt][nt], 0, 0, 0);
            }
        }
        cur ^= 1;
    }
#pragma unroll
    for (int mt = 0; mt < 2; ++mt)
#pragma unroll
        for (int r = 0; r < 4; ++r) {
            int row = mtile * 128 + w * 32 + mt * 16 + (lane >> 4) * 4 + r;
#pragma unroll
            for (int nt = 0; nt < 4; ++nt) {
                int col = ntile * 64 + nt * 16 + (lane & 15);
                C[(long)row * N + col] = f2bf(acc[mt][nt][r]);
            }
        }
}

// ---------------------------------------------------------------------------
// ph3 bf16 MFMA GEMM, A = flat [32000][512] bf16 (F). 128x64 tile, KT=8.
// A staged via pre-swizzled global src -> linear LDS; frag reads XOR-swizzled
// (conflict-free). C fp32 [B,T,OUT] with bias.
// ---------------------------------------------------------------------------
__global__ __launch_bounds__(256) void gemm_out_flat(
    const unsigned short* __restrict__ Af, const unsigned short* __restrict__ Bm,
    float* __restrict__ C, const float* __restrict__ bias)
{
    constexpr int KT = 8;
    __shared__ unsigned short Asl[2][8192];   // [row 128][kq 8][e 8] swizzled
    __shared__ unsigned short Bsl[2][4096];

    const int tid = threadIdx.x, lane = tid & 63, w = tid >> 6;
    const int ntile = blockIdx.x, mtile = blockIdx.y;
    const unsigned short* Ab = Af + (long)mtile * 128 * Hn;
    const unsigned short* Bbase = Bm + (long)ntile * KT * 4096;

    auto stageA = [&](int kt, int buf) {
#pragma unroll
        for (int j = 0; j < 4; ++j) {
            int c = tid + 256 * j;                // chunk: row=c>>3, slot=c&7
            int row = c >> 3, slot = c & 7;
            int kqs = slot ^ (row & 7);           // pre-swizzled source kq
            gl_lds16(Ab + (long)row * Hn + kt * 64 + kqs * 8,
                     &Asl[buf][c * 8]);
        }
    };
    auto stageB = [&](int kt, int buf) {
#pragma unroll
        for (int j = 0; j < 2; ++j) {
            int c = tid + 256 * j;
            gl_lds16(Bbase + (long)kt * 4096 + (long)c * 8, &Bsl[buf][c * 8]);
        }
    };

    f32x4 acc[2][4] = {};
    stageA(0, 0); stageB(0, 0);
    int cur = 0;
#pragma unroll
    for (int kt = 0; kt < KT; ++kt) {
        __syncthreads();
        if (kt + 1 < KT) { stageA(kt + 1, cur ^ 1); stageB(kt + 1, cur ^ 1); }
#pragma unroll
        for (int ks = 0; ks < 2; ++ks) {
            const int kq = ks * 4 + (lane >> 4);
            short8v bfr[4];
#pragma unroll
            for (int nt = 0; nt < 4; ++nt)
                bfr[nt] = *(const short8v*)
                    &Bsl[cur][kq * 512 + (nt * 16 + (lane & 15)) * 8];
#pragma unroll
            for (int mt = 0; mt < 2; ++mt) {
                int row = w * 32 + mt * 16 + (lane & 15);
                short8v afr = *(const short8v*)((const char*)&Asl[cur][0]
                    + ((unsigned)(row * 128 + kq * 16)
                       ^ ((unsigned)(row & 7) << 4)));
#pragma unroll
                for (int nt = 0; nt < 4; ++nt)
                    acc[mt][nt] = __builtin_amdgcn_mfma_f32_16x16x32_bf16(
                        afr, bfr[nt], acc[mt][nt], 0, 0, 0);
            }
        }
        cur ^= 1;
    }
#pragma unroll
    for (int mt = 0; mt < 2; ++mt)
#pragma unroll
        for (int r = 0; r < 4; ++r) {
            int row = mtile * 128 + w * 32 + mt * 16 + (lane >> 4) * 4 + r;
            long crow = ((long)(row & 31) * Tn + (row >> 5)) * (long)OUTn;
#pragma unroll
            for (int nt = 0; nt < 4; ++nt) {
                int col = ntile * 64 + nt * 16 + (lane & 15);
                C[crow + col] = acc[mt][nt][r] + bias[col];
            }
        }
}

// ---------------------------------------------------------------------------
// Phase 2: 32 blocks (one per batch b), 512 threads (8 waves).
// F written FLAT bf16 (coalesced). Sy transposed [h][24] (vector reads).
// ff-syn in regs (bf16 SYN). W wreg as R9 (allocator streams it; accepted).
// One barrier per stage.
// ---------------------------------------------------------------------------
__global__ __launch_bounds__(512) void phase2_bpart(
    const unsigned char* __restrict__ Wq,    // [512 n][512 k] fp8
    const unsigned short* __restrict__ SYN,  // [T][B][H] bf16
    unsigned short* __restrict__ Fb,         // [32000][512] bf16 flat
    const float* __restrict__ tkm, const float* __restrict__ thr,
    const float* __restrict__ aamp, const float* __restrict__ tascr,
    const float* __restrict__ tkasc)
{
    __shared__ unsigned char A_lds[2][32 * 512];  // 2 x 16 KB fp8, swizzled
    __shared__ unsigned short Sy[Hn][24];         // 24 KB bf16, [h][s]

    const int tid = threadIdx.x;
    const int b = blockIdx.x;
    const int lane = tid & 63, w = tid >> 6;

    // zero both A buffers (covers pad rows 20..31 forever)
#pragma unroll
    for (int j = 0; j < 4; ++j)
        *(uint4*)(&A_lds[0][0] + (j * 512 + tid) * 16) = make_uint4(0u,0u,0u,0u);

    // ---- W fragments (R9 semantics: allocator may stream; accepted)
    long long wreg[16][4];
#pragma unroll
    for (int kt = 0; kt < 16; ++kt)
#pragma unroll
        for (int nt = 0; nt < 4; ++nt) {
            int n = w * 64 + nt * 16 + (lane & 15);
            int kk = kt * 32 + (lane >> 4) * 8;
            wreg[kt][nt] = *(const long long*)&Wq[(long)n * Hn + kk];
        }

    // ---- per-thread ew params: h = tid
    const int h = tid;
    const float dkm  = sigmoidf_(tkm[h]);
    const float th   = thr[h];
    const float am0  = aamp[h],       am1 = aamp[Hn + h];
    const float rr0  = 1.f - 2.f * sigmoidf_(tascr[h]);
    const float rr1  = 1.f - 2.f * sigmoidf_(tascr[Hn + h]);
    const float dk0  = sigmoidf_(tkasc[h]);
    const float dk1  = sigmoidf_(tkasc[Hn + h]);
    const float kR   = dkm * Rc;
    float volt = 0.f, fir = 0.f, a0 = 0.f, a1 = 0.f;

    // A-frag byte offsets
    const int ar0 = lane & 15, ar1 = 16 + (lane & 15);
    const unsigned a0base = (unsigned)(ar0 * 512 + (lane >> 4) * 8);
    const unsigned a1base = (unsigned)(ar1 * 512 + (lane >> 4) * 8);
    const unsigned swz0 = (unsigned)((ar0 & 7) << 3);
    const unsigned swz1 = (unsigned)((ar1 & 7) << 3);

    __syncthreads();

#pragma unroll 1
    for (int k = 0; k < NBLK; ++k) {
        // ff-syn loads (bf16, stride BH): issued early, consumed after GEMM
        const unsigned short* synk = SYN + (long)k * DELAY * BH
                                     + (long)b * Hn + h;
        float ff[DELAY];
#pragma unroll
        for (int s = 0; s < DELAY; ++s)
            ff[s] = bf2f(synk[(long)s * BH]);

        if (k > 0) {
            const unsigned char* Ab = &A_lds[k & 1][0];
            f32x4 acc[2][4] = {};
#pragma unroll
            for (int kt = 0; kt < 16; ++kt) {
                long long afr0 = *(const long long*)(Ab + ((a0base + kt * 32) ^ swz0));
                long long afr1 = *(const long long*)(Ab + ((a1base + kt * 32) ^ swz1));
#pragma unroll
                for (int nt = 0; nt < 4; ++nt) {
                    acc[0][nt] = __builtin_amdgcn_mfma_f32_16x16x32_fp8_fp8(
                        afr0, wreg[kt][nt], acc[0][nt], 0, 0, 0);
                    acc[1][nt] = __builtin_amdgcn_mfma_f32_16x16x32_fp8_fp8(
                        afr1, wreg[kt][nt], acc[1][nt], 0, 0, 0);
                }
            }
            // epilogue -> Sy[h][s] (transposed, wave-local cols)
#pragma unroll
            for (int mt = 0; mt < 2; ++mt)
#pragma unroll
                for (int r = 0; r < 4; ++r) {
                    int s = mt * 16 + (lane >> 4) * 4 + r;
                    if (s < DELAY) {
#pragma unroll
                        for (int nt = 0; nt < 4; ++nt) {
                            int c = w * 64 + nt * 16 + (lane & 15);
                            Sy[c][s] = f2bf(acc[mt][nt][r]);
                        }
                    }
                }
        }

        // ---- lateral values: 2x ds_read_b128 + 1x b64 (own wave's strip)
        float latv[DELAY];
        if (k > 0) {
            const unsigned short* syrow = &Sy[h][0];
            short8v v0 = *(const short8v*)(syrow);       // s 0..7
            short8v v1 = *(const short8v*)(syrow + 8);   // s 8..15
            uint2  v2 = *(const uint2*)(syrow + 16);     // s 16..19
            const unsigned short* p2 = (const unsigned short*)&v2;
#pragma unroll
            for (int i = 0; i < 8; ++i) latv[i]     = bf2f((unsigned short)v0[i]);
#pragma unroll
            for (int i = 0; i < 8; ++i) latv[8 + i] = bf2f((unsigned short)v1[i]);
#pragma unroll
            for (int i = 0; i < 4; ++i) latv[16 + i] = bf2f(p2[i]);
        } else {
#pragma unroll
            for (int i = 0; i < DELAY; ++i) latv[i] = 0.f;
        }

        // ---- elementwise recurrence (20 steps)
        unsigned char* An = &A_lds[(k + 1) & 1][0];
        unsigned short* Fo = Fb + ((long)(k * DELAY * Bsz + b)) * Hn + h;
#pragma unroll
        for (int s = 0; s < DELAY; ++s) {
            float sv = ff[s] + latv[s];
            a0 = a0 * (rr0 * fir * DTc + (1.f - dk0)) + am0 * fir * DTc;
            a1 = a1 * (rr1 * fir * DTc + (1.f - dk1)) + am1 * fir * DTc;
            volt = volt * (1.f - dkm - fir) + kR * (sv + a0 + a1);
            fir = sigfast_(volt - th);
            An[(unsigned)(s * 512 + h) ^ ((unsigned)(s & 7) << 3)] = f2e4m3(fir);
            Fo[(long)s * BH] = f2bf(fir);   // coalesced: 512 thr x 2B = 1KB row
        }
        __syncthreads();   // A_lds[(k+1)&1] complete; Sy reads done
    }
}

extern "C" void kernel_launch(void* const* d_in, const int* in_sizes, int n_in,
                              void* d_out, int out_size, void* d_ws, size_t ws_size,
                              hipStream_t stream) {
    const float* input = (const float*)d_in[0];   // [B,T,IN]
    const float* w_iv  = (const float*)d_in[1];   // [IN,H]
    const float* w_lat = (const float*)d_in[2];   // [H,H]
    const float* thr   = (const float*)d_in[3];   // [1,H]
    const float* tkm   = (const float*)d_in[4];   // [1,H]
    const float* aamp  = (const float*)d_in[5];   // [A,1,H]
    const float* tascr = (const float*)d_in[6];   // [A,1,H]
    const float* tkasc = (const float*)d_in[7];   // [A,1,H]
    const float* outw  = (const float*)d_in[8];   // [H,OUT]
    const float* outb  = (const float*)d_in[9];   // [OUT]
    float* out = (float*)d_out;                   // [B,T,OUT]

    const size_t TBH = (size_t)Tn * BH;           // 16,384,000
    unsigned short* SYNb = (unsigned short*)d_ws;         // [T][B][H] bf16
    unsigned short* Fb   = SYNb + TBH;                    // [32000][512] bf16
    unsigned short* Abf  = Fb + TBH;                      // blocked bf16 input
    unsigned char* Wq    = (unsigned char*)(Abf + (size_t)8192 * 1000);
    unsigned short* Wivb = (unsigned short*)(Wq + (size_t)Hn * Hn);
    unsigned short* Wowb = Wivb + (size_t)INn * Hn;

    // Phase 0: conversions
    cvt_in<<<1000, 256, 0, stream>>>(input, Abf);
    cvt_b<4, 512><<<64, 256, 0, stream>>>(w_iv, Wivb);
    cvt_b<8, 128><<<32, 256, 0, stream>>>(outw, Wowb);
    wlat_cvt<<<256, 256, 0, stream>>>(w_lat, Wq);

    // Phase 1: SYN(bf16) = input @ W_iv  (M=32000, N=512, K=256)
    gemm_ph1<4><<<dim3(8, 250), 256, 0, stream>>>(Abf, Wivb, SYNb, Hn);

    // Phase 2: 32 independent per-batch blocks
    phase2_bpart<<<32, 512, 0, stream>>>(Wq, SYNb, Fb,
                                         tkm, thr, aamp, tascr, tkasc);

    // Phase 3: out = F_flat @ out_w + out_b  (M=32000, N=128, K=512)
    gemm_out_flat<<<dim3(2, 250), 256, 0, stream>>>(Fb, Wowb, out, outb);
}

// Round 16
// 253.588 us; speedup vs baseline: 2.9748x; 1.1264x over previous
//
#include <hip/hip_runtime.h>
#include <math.h>

// GLIFR (BNNFC) : B=32, T=1000, IN=256, H=512, OUT=128, A=2, DELAY=20
//  cvts: input->Abf (blocked bf16), W_iv/out_w -> blocked bf16,
//        W_lat -> Wq4 [h][k] fp4 e2m1 (x32 pre-scale, global scale 2^-5)
//  ph1: SYN(bf16 flat) = input @ W_iv   (bf16 MFMA GEMM)
//  ph2: 32 blocks, 512 thr. R16: W RESIDENT IN LDS as fp4 (128 KB, loaded
//       once) via mfma_scale_f32_16x16x128_f8f6f4 (A fp8, B fp4, scales=1).
//       R7-R15 established W streaming (~3.8us/stage scratch/L2) as the
//       dominant residual. Uniform scales + same-position A/B placement
//       make the HW k-permutation cancel. Single A buffer (2 barriers).
//  ph3: out = F_flat @ out_w + out_b    (bf16 MFMA GEMM)

constexpr int Bsz   = 32;
constexpr int Tn    = 1000;
constexpr int INn   = 256;
constexpr int Hn    = 512;
constexpr int OUTn  = 128;
constexpr int DELAY = 20;
constexpr int NBLK  = Tn / DELAY;   // 50
constexpr float DTc = 0.05f;
constexpr float Rc  = 0.1f;
constexpr int BH = Bsz * Hn;                  // 16384

typedef __attribute__((ext_vector_type(8))) short short8v;  // 8 bf16
typedef __attribute__((ext_vector_type(4))) float f32x4;
typedef __attribute__((ext_vector_type(8))) int int8v;

__device__ __forceinline__ float sigmoidf_(float x) {
    return 1.0f / (1.0f + expf(-x));
}
__device__ __forceinline__ float sigfast_(float x) {
    return __builtin_amdgcn_rcpf(1.0f + __builtin_amdgcn_exp2f(x * -1.44269504f));
}
__device__ __forceinline__ float bf2f(unsigned short u) {
    return __uint_as_float(((unsigned)u) << 16);
}
__device__ __forceinline__ unsigned short f2bf(float f) {
    unsigned x = __float_as_uint(f);
    return (unsigned short)((x + 0x7fff + ((x >> 16) & 1)) >> 16);  // RNE
}
// OCP e4m3fn encode: HW packed convert if available, else sw RNE
__device__ __forceinline__ unsigned char f2e4m3(float x) {
#if __has_builtin(__builtin_amdgcn_cvt_pk_fp8_f32)
    return (unsigned char)(__builtin_amdgcn_cvt_pk_fp8_f32(x, 0.f, 0, false) & 0xff);
#else
    unsigned b = __float_as_uint(x);
    unsigned s = (b >> 31) << 7;
    b &= 0x7fffffffu;
    unsigned code;
    if (__uint_as_float(b) < 0.015625f) {
        code = (unsigned)__float2int_rn(__uint_as_float(b) * 512.0f);
    } else {
        unsigned r = b + 0x7ffffu + ((b >> 20) & 1);
        int e = (int)(r >> 23) - 127;
        code = (unsigned)(((e + 7) << 3) | ((r >> 20) & 7));
    }
    return (unsigned char)(s | code);
#endif
}
// fp4 e2m1 encode of x*32 (global scale 2^-5 baked in), nearest on the grid
__device__ __forceinline__ unsigned f4enc(float x) {
    float y = x * 32.0f;
    unsigned s = (__float_as_uint(y) >> 31) << 3;
    float a = fabsf(y);
    unsigned c;
    if      (a < 0.25f) c = 0;      // 0
    else if (a < 0.75f) c = 1;      // 0.5
    else if (a < 1.25f) c = 2;      // 1.0
    else if (a < 1.75f) c = 3;      // 1.5
    else if (a < 2.5f)  c = 4;      // 2
    else if (a < 3.5f)  c = 5;      // 3
    else if (a < 5.0f)  c = 6;      // 4
    else                c = 7;      // 6
    return s | c;
}
__device__ __forceinline__ void gl_lds16(const void* g, void* l) {
    __builtin_amdgcn_global_load_lds(
        (const __attribute__((address_space(1))) void*)g,
        (__attribute__((address_space(3))) void*)l, 16, 0, 0);
}

// ---------------------------------------------------------------------------
// input [B,T,IN] fp32 -> Abf blocked bf16 [mtile 250][kt 4][kq 8][row 128][e 8]
// ---------------------------------------------------------------------------
__global__ __launch_bounds__(256) void cvt_in(
    const float* __restrict__ in, unsigned short* __restrict__ Abf)
{
    __shared__ float t[128][65];
    const int tid = threadIdx.x;
    const int mtile = blockIdx.x >> 2, kt = blockIdx.x & 3;
    const int rr = tid >> 4, cc = (tid & 15) * 4;
#pragma unroll
    for (int j = 0; j < 8; ++j) {
        int row = j * 16 + rr;
        int m = mtile * 128 + row;
        float4 v = *(const float4*)
            &in[((long)(m & 31) * Tn + (m >> 5)) * INn + kt * 64 + cc];
        t[row][cc] = v.x; t[row][cc + 1] = v.y;
        t[row][cc + 2] = v.z; t[row][cc + 3] = v.w;
    }
    __syncthreads();
    unsigned short* dst = Abf + (long)(mtile * 4 + kt) * 8192;
#pragma unroll
    for (int j = 0; j < 4; ++j) {
        int q = tid + 256 * j;
        int kq = q >> 7, row = q & 127;
        short8v o;
#pragma unroll
        for (int i = 0; i < 8; ++i) o[i] = (short)f2bf(t[row][kq * 8 + i]);
        *(short8v*)&dst[(long)q * 8] = o;
    }
}

// ---------------------------------------------------------------------------
// Weight [K][NG] fp32 -> blocked bf16 B^T tiles [ntile][KT_][kq 8][n 64][e 8]
// ---------------------------------------------------------------------------
template<int KT_, int NG>
__global__ __launch_bounds__(256) void cvt_b(
    const float* __restrict__ Wg, unsigned short* __restrict__ Bb)
{
    int c = blockIdx.x * 256 + threadIdx.x;
    int n = c & 63;
    int c2 = c >> 6;
    int kq = c2 & 7;
    int c3 = c2 >> 3;
    int kt = c3 % KT_, ntile = c3 / KT_;
    short8v o;
#pragma unroll
    for (int i = 0; i < 8; ++i)
        o[i] = (short)f2bf(Wg[(long)(kt * 64 + kq * 8 + i) * NG + ntile * 64 + n]);
    *(short8v*)&Bb[(long)c * 8] = o;
}

// ---------------------------------------------------------------------------
// W_lat [k 512][h 512] fp32 -> Wq4 [h 512][k/2 256] fp4-packed (x32 scale).
// Block: 32 h x 64 k. Low nibble = even k.
// ---------------------------------------------------------------------------
__global__ __launch_bounds__(256) void wlat_cvt4(
    const float* __restrict__ W, unsigned char* __restrict__ Wq4)
{
    __shared__ float tile[64][33];
    const int tid = threadIdx.x;
    const int hx = blockIdx.x & 15, ky = blockIdx.x >> 4;   // 16 x 8
    const int h0 = hx * 32, k0 = ky * 64;
#pragma unroll
    for (int j = 0; j < 8; ++j) {
        int idx = j * 256 + tid;
        int kk = idx >> 5, hh = idx & 31;
        tile[kk][hh] = W[(long)(k0 + kk) * Hn + h0 + hh];
    }
    __syncthreads();
#pragma unroll
    for (int j = 0; j < 4; ++j) {
        int o = j * 256 + tid;
        int hh = o >> 5, kb = o & 31;
        unsigned lo = f4enc(tile[2 * kb][hh]);
        unsigned hi = f4enc(tile[2 * kb + 1][hh]);
        Wq4[(long)(h0 + hh) * 256 + ky * 32 + kb] = (unsigned char)(lo | (hi << 4));
    }
}

// ---------------------------------------------------------------------------
// ph1 bf16 MFMA GEMM: 128x64 tile, BK=64, 256 thr. A blocked, C bf16 flat.
// ---------------------------------------------------------------------------
template<int KT>
__global__ __launch_bounds__(256) void gemm_ph1(
    const unsigned short* __restrict__ A, const unsigned short* __restrict__ Bm,
    unsigned short* __restrict__ C, int N)
{
    __shared__ unsigned short Asl[2][8192];
    __shared__ unsigned short Bsl[2][4096];

    const int tid = threadIdx.x, lane = tid & 63, w = tid >> 6;
    const int ntile = blockIdx.x, mtile = blockIdx.y;
    const unsigned short* Abase = A + (long)mtile * KT * 8192;
    const unsigned short* Bbase = Bm + (long)ntile * KT * 4096;

    auto stageA = [&](int kt, int buf) {
#pragma unroll
        for (int j = 0; j < 4; ++j) {
            int c = tid + 256 * j;
            gl_lds16(Abase + (long)kt * 8192 + (long)c * 8, &Asl[buf][c * 8]);
        }
    };
    auto stageB = [&](int kt, int buf) {
#pragma unroll
        for (int j = 0; j < 2; ++j) {
            int c = tid + 256 * j;
            gl_lds16(Bbase + (long)kt * 4096 + (long)c * 8, &Bsl[buf][c * 8]);
        }
    };

    f32x4 acc[2][4] = {};
    stageA(0, 0); stageB(0, 0);
    int cur = 0;
#pragma unroll
    for (int kt = 0; kt < KT; ++kt) {
        __syncthreads();
        if (kt + 1 < KT) { stageA(kt + 1, cur ^ 1); stageB(kt + 1, cur ^ 1); }
#pragma unroll
        for (int ks = 0; ks < 2; ++ks) {
            const int kq = ks * 4 + (lane >> 4);
            short8v bfr[4];
#pragma unroll
            for (int nt = 0; nt < 4; ++nt)
                bfr[nt] = *(const short8v*)
                    &Bsl[cur][kq * 512 + (nt * 16 + (lane & 15)) * 8];
#pragma unroll
            for (int mt = 0; mt < 2; ++mt) {
                short8v afr = *(const short8v*)
                    &Asl[cur][kq * 1024 + (w * 32 + mt * 16 + (lane & 15)) * 8];
#pragma unroll
                for (int nt = 0; nt < 4; ++nt)
                    acc[mt][nt] = __builtin_amdgcn_mfma_f32_16x16x32_bf16(
                        afr, bfr[nt], acc[mt][nt], 0, 0, 0);
            }
        }
        cur ^= 1;
    }
#pragma unroll
    for (int mt = 0; mt < 2; ++mt)
#pragma unroll
        for (int r = 0; r < 4; ++r) {
            int row = mtile * 128 + w * 32 + mt * 16 + (lane >> 4) * 4 + r;
#pragma unroll
            for (int nt = 0; nt < 4; ++nt) {
                int col = ntile * 64 + nt * 16 + (lane & 15);
                C[(long)row * N + col] = f2bf(acc[mt][nt][r]);
            }
        }
}

// ---------------------------------------------------------------------------
// ph3 bf16 MFMA GEMM, A = flat [32000][512] bf16 (F). 128x64 tile, KT=8.
// ---------------------------------------------------------------------------
__global__ __launch_bounds__(256) void gemm_out_flat(
    const unsigned short* __restrict__ Af, const unsigned short* __restrict__ Bm,
    float* __restrict__ C, const float* __restrict__ bias)
{
    constexpr int KT = 8;
    __shared__ unsigned short Asl[2][8192];
    __shared__ unsigned short Bsl[2][4096];

    const int tid = threadIdx.x, lane = tid & 63, w = tid >> 6;
    const int ntile = blockIdx.x, mtile = blockIdx.y;
    const unsigned short* Ab = Af + (long)mtile * 128 * Hn;
    const unsigned short* Bbase = Bm + (long)ntile * KT * 4096;

    auto stageA = [&](int kt, int buf) {
#pragma unroll
        for (int j = 0; j < 4; ++j) {
            int c = tid + 256 * j;
            int row = c >> 3, slot = c & 7;
            int kqs = slot ^ (row & 7);
            gl_lds16(Ab + (long)row * Hn + kt * 64 + kqs * 8,
                     &Asl[buf][c * 8]);
        }
    };
    auto stageB = [&](int kt, int buf) {
#pragma unroll
        for (int j = 0; j < 2; ++j) {
            int c = tid + 256 * j;
            gl_lds16(Bbase + (long)kt * 4096 + (long)c * 8, &Bsl[buf][c * 8]);
        }
    };

    f32x4 acc[2][4] = {};
    stageA(0, 0); stageB(0, 0);
    int cur = 0;
#pragma unroll
    for (int kt = 0; kt < KT; ++kt) {
        __syncthreads();
        if (kt + 1 < KT) { stageA(kt + 1, cur ^ 1); stageB(kt + 1, cur ^ 1); }
#pragma unroll
        for (int ks = 0; ks < 2; ++ks) {
            const int kq = ks * 4 + (lane >> 4);
            short8v bfr[4];
#pragma unroll
            for (int nt = 0; nt < 4; ++nt)
                bfr[nt] = *(const short8v*)
                    &Bsl[cur][kq * 512 + (nt * 16 + (lane & 15)) * 8];
#pragma unroll
            for (int mt = 0; mt < 2; ++mt) {
                int row = w * 32 + mt * 16 + (lane & 15);
                short8v afr = *(const short8v*)((const char*)&Asl[cur][0]
                    + ((unsigned)(row * 128 + kq * 16)
                       ^ ((unsigned)(row & 7) << 4)));
#pragma unroll
                for (int nt = 0; nt < 4; ++nt)
                    acc[mt][nt] = __builtin_amdgcn_mfma_f32_16x16x32_bf16(
                        afr, bfr[nt], acc[mt][nt], 0, 0, 0);
            }
        }
        cur ^= 1;
    }
#pragma unroll
    for (int mt = 0; mt < 2; ++mt)
#pragma unroll
        for (int r = 0; r < 4; ++r) {
            int row = mtile * 128 + w * 32 + mt * 16 + (lane >> 4) * 4 + r;
            long crow = ((long)(row & 31) * Tn + (row >> 5)) * (long)OUTn;
#pragma unroll
            for (int nt = 0; nt < 4; ++nt) {
                int col = ntile * 64 + nt * 16 + (lane & 15);
                C[crow + col] = acc[mt][nt][r] + bias[col];
            }
        }
}

// ---------------------------------------------------------------------------
// Phase 2: 32 blocks (one per batch b), 512 threads (8 waves).
// W fp4 resident in LDS (128 KB, staged once). mfma_scale 16x16x128 f8f6f4:
// A fp8 (firing, LDS single buffer [20][512]), B fp4, scales uniform 127
// (x1), epilogue x 2^-5. Sy [512][20] bf16. 2 barriers/stage.
// ---------------------------------------------------------------------------
__global__ __launch_bounds__(512) void phase2_bpart(
    const unsigned char* __restrict__ Wq4,   // [512 n][256 B] fp4 packed
    const unsigned short* __restrict__ SYN,  // [T][B][H] bf16
    unsigned short* __restrict__ Fb,         // [32000][512] bf16 flat
    const float* __restrict__ tkm, const float* __restrict__ thr,
    const float* __restrict__ aamp, const float* __restrict__ tascr,
    const float* __restrict__ tkasc)
{
    __shared__ unsigned char Wl[512 * 256];   // 128 KB fp4, swizzled
    __shared__ unsigned char Afp8[20 * 512];  // 10 KB fp8 firing, swizzled
    __shared__ unsigned short Sy[512 * 20];   // 20 KB bf16 [n][t]

    const int tid = threadIdx.x;
    const int b = blockIdx.x;
    const int lane = tid & 63, w = tid >> 6;

    // ---- stage W fp4 into LDS once (swizzle ^((n&7)<<4) per 16B chunk)
#pragma unroll
    for (int i = 0; i < 16; ++i) {
        int c = i * 512 + tid;                // 16B chunk id, 8192 total
        int n = c >> 4, ci = c & 15;
        int4 v = *(const int4*)(Wq4 + (long)n * 256 + ci * 16);
        *(int4*)(&Wl[(unsigned)(n * 256 + ci * 16) ^ ((unsigned)(n & 7) << 4)]) = v;
    }

    // ---- per-thread ew params: h = tid
    const int h = tid;
    const float dkm  = sigmoidf_(tkm[h]);
    const float th   = thr[h];
    const float am0  = aamp[h],       am1 = aamp[Hn + h];
    const float rr0  = 1.f - 2.f * sigmoidf_(tascr[h]);
    const float rr1  = 1.f - 2.f * sigmoidf_(tascr[Hn + h]);
    const float dk0  = sigmoidf_(tkasc[h]);
    const float dk1  = sigmoidf_(tkasc[Hn + h]);
    const float kR   = dkm * Rc;
    float volt = 0.f, fir = 0.f, a0 = 0.f, a1 = 0.f;

    // frag address invariants
    const int g = lane >> 4;                  // k-group 0..3
    const int r0 = lane & 15, r1 = 16 + (lane & 15);
    const unsigned a0b = (unsigned)(r0 * 512 + g * 32);
    const unsigned a1b = (unsigned)(r1 * 512 + g * 32);
    const unsigned s0 = (unsigned)((r0 & 7) << 4);
    const unsigned s1 = (unsigned)((r1 & 7) << 4);
    unsigned wboff[4], wbswz[4];
#pragma unroll
    for (int nt = 0; nt < 4; ++nt) {
        int n = w * 64 + nt * 16 + (lane & 15);
        wboff[nt] = (unsigned)(n * 256 + g * 16);
        wbswz[nt] = (unsigned)((n & 7) << 4);
    }

    __syncthreads();   // W staged; Afp8 written by stage-0 ew before first GEMM

#pragma unroll 1
    for (int k = 0; k < NBLK; ++k) {
        // ff-syn loads (bf16): issued early, consumed in ew
        const unsigned short* synk = SYN + (long)k * DELAY * BH
                                     + (long)b * Hn + h;
        float ff[DELAY];
#pragma unroll
        for (int s = 0; s < DELAY; ++s)
            ff[s] = bf2f(synk[(long)s * BH]);

        if (k > 0) {
            f32x4 acc[2][4] = {};
#pragma unroll
            for (int kt = 0; kt < 4; ++kt) {     // K tiles of 128
                int8v va0 = {}, va1 = {};
                {
                    unsigned lo = (a0b + kt * 128) ^ s0;
                    unsigned hi = (a0b + kt * 128 + 16) ^ s0;
                    *(int4*)&va0       = *(const int4*)(&Afp8[0] + lo);
                    *((int4*)&va0 + 1) = *(const int4*)(&Afp8[0] + hi);
                    lo = (a1b + kt * 128) ^ s1;
                    hi = (a1b + kt * 128 + 16) ^ s1;
                    *(int4*)&va1       = *(const int4*)(&Afp8[0] + lo);
                    *((int4*)&va1 + 1) = *(const int4*)(&Afp8[0] + hi);
                }
#pragma unroll
                for (int nt = 0; nt < 4; ++nt) {
                    int8v vb = {};
                    *(int4*)&vb = *(const int4*)(&Wl[0]
                        + ((wboff[nt] + kt * 64) ^ wbswz[nt]));
                    acc[0][nt] = __builtin_amdgcn_mfma_scale_f32_16x16x128_f8f6f4(
                        va0, vb, acc[0][nt], 0, 4, 0, 127, 0, 127);
                    acc[1][nt] = __builtin_amdgcn_mfma_scale_f32_16x16x128_f8f6f4(
                        va1, vb, acc[1][nt], 0, 4, 0, 127, 0, 127);
                }
            }
            // epilogue -> Sy[n][t], x 2^-5 dequant. C frag: col=lane&15,
            // row(t) = mt*16 + (lane>>4)*4 + r
#pragma unroll
            for (int mt = 0; mt < 2; ++mt)
#pragma unroll
                for (int r = 0; r < 4; ++r) {
                    int t = mt * 16 + (lane >> 4) * 4 + r;
                    if (t < DELAY) {
#pragma unroll
                        for (int nt = 0; nt < 4; ++nt) {
                            int n = w * 64 + nt * 16 + (lane & 15);
                            Sy[n * 20 + t] = f2bf(acc[mt][nt][r] * 0.03125f);
                        }
                    }
                }
        }
        __syncthreads();   // all GEMM A-reads done; Sy (wave-local) visible

        // ---- lateral values: 5x ds_read_b64 from own Sy row
        float latv[DELAY];
        if (k > 0) {
            const unsigned short* syp = &Sy[h * 20];
#pragma unroll
            for (int j = 0; j < 5; ++j) {
                uint2 q = *(const uint2*)(syp + j * 4);
                latv[j * 4 + 0] = bf2f((unsigned short)(q.x & 0xffff));
                latv[j * 4 + 1] = bf2f((unsigned short)(q.x >> 16));
                latv[j * 4 + 2] = bf2f((unsigned short)(q.y & 0xffff));
                latv[j * 4 + 3] = bf2f((unsigned short)(q.y >> 16));
            }
        } else {
#pragma unroll
            for (int i = 0; i < DELAY; ++i) latv[i] = 0.f;
        }

        // ---- elementwise recurrence (20 steps); writes next A + flat F
        unsigned short* Fo = Fb + ((long)(k * DELAY * Bsz + b)) * Hn + h;
#pragma unroll
        for (int s = 0; s < DELAY; ++s) {
            float sv = ff[s] + latv[s];
            a0 = a0 * (rr0 * fir * DTc + (1.f - dk0)) + am0 * fir * DTc;
            a1 = a1 * (rr1 * fir * DTc + (1.f - dk1)) + am1 * fir * DTc;
            volt = volt * (1.f - dkm - fir) + kR * (sv + a0 + a1);
            fir = sigfast_(volt - th);
            Afp8[(unsigned)(s * 512 + h) ^ ((unsigned)(s & 7) << 4)] = f2e4m3(fir);
            Fo[(long)s * BH] = f2bf(fir);
        }
        __syncthreads();   // A complete for next stage's GEMM
    }
}

extern "C" void kernel_launch(void* const* d_in, const int* in_sizes, int n_in,
                              void* d_out, int out_size, void* d_ws, size_t ws_size,
                              hipStream_t stream) {
    const float* input = (const float*)d_in[0];   // [B,T,IN]
    const float* w_iv  = (const float*)d_in[1];   // [IN,H]
    const float* w_lat = (const float*)d_in[2];   // [H,H]
    const float* thr   = (const float*)d_in[3];   // [1,H]
    const float* tkm   = (const float*)d_in[4];   // [1,H]
    const float* aamp  = (const float*)d_in[5];   // [A,1,H]
    const float* tascr = (const float*)d_in[6];   // [A,1,H]
    const float* tkasc = (const float*)d_in[7];   // [A,1,H]
    const float* outw  = (const float*)d_in[8];   // [H,OUT]
    const float* outb  = (const float*)d_in[9];   // [OUT]
    float* out = (float*)d_out;                   // [B,T,OUT]

    const size_t TBH = (size_t)Tn * BH;           // 16,384,000
    unsigned short* SYNb = (unsigned short*)d_ws;         // [T][B][H] bf16
    unsigned short* Fb   = SYNb + TBH;                    // [32000][512] bf16
    unsigned short* Abf  = Fb + TBH;                      // blocked bf16 input
    unsigned char* Wq4   = (unsigned char*)(Abf + (size_t)8192 * 1000);
    unsigned short* Wivb = (unsigned short*)(Wq4 + (size_t)Hn * 256);
    unsigned short* Wowb = Wivb + (size_t)INn * Hn;

    // Phase 0: conversions
    cvt_in<<<1000, 256, 0, stream>>>(input, Abf);
    cvt_b<4, 512><<<64, 256, 0, stream>>>(w_iv, Wivb);
    cvt_b<8, 128><<<32, 256, 0, stream>>>(outw, Wowb);
    wlat_cvt4<<<128, 256, 0, stream>>>(w_lat, Wq4);

    // Phase 1: SYN(bf16) = input @ W_iv  (M=32000, N=512, K=256)
    gemm_ph1<4><<<dim3(8, 250), 256, 0, stream>>>(Abf, Wivb, SYNb, Hn);

    // Phase 2: 32 independent per-batch blocks, W fp4 LDS-resident
    phase2_bpart<<<32, 512, 0, stream>>>(Wq4, SYNb, Fb,
                                         tkm, thr, aamp, tascr, tkasc);

    // Phase 3: out = F_flat @ out_w + out_b  (M=32000, N=128, K=512)
    gemm_out_flat<<<dim3(2, 250), 256, 0, stream>>>(Fb, Wowb, out, outb);
}

// Round 18
// 247.805 us; speedup vs baseline: 3.0442x; 1.0233x over previous
//
#include <hip/hip_runtime.h>
#include <math.h>

// GLIFR (BNNFC) : B=32, T=1000, IN=256, H=512, OUT=128, A=2, DELAY=20
//  cvts: input->Abf (blocked bf16), W_iv/out_w -> blocked bf16,
//        W_lat -> Wq4 [h][k] fp4 e2m1 (x32 pre-scale, global scale 2^-5)
//  ph1: SYN(bf16, [b][t][h]) = input @ W_iv   (bf16 MFMA GEMM, BT C-map)
//  ph2: 32 blocks, 512 thr. W fp4 LDS-resident (R16). R17: A double-buffer
//       (2x10KB fp8) -> Sy wave-local -> ONE barrier/stage; Sy fp8 via HW
//       cvt_pk_fp8/cvt_f32_fp8 (VALU cut); SYN [b][t][h] -> imm-folded ff.
//  R18 fix: cvt_f32_fp8 byte-select must be a literal -> template<int SEL>.
//  ph3: out = F_flat @ out_w + out_b    (bf16 MFMA GEMM)

constexpr int Bsz   = 32;
constexpr int Tn    = 1000;
constexpr int INn   = 256;
constexpr int Hn    = 512;
constexpr int OUTn  = 128;
constexpr int DELAY = 20;
constexpr int NBLK  = Tn / DELAY;   // 50
constexpr float DTc = 0.05f;
constexpr float Rc  = 0.1f;
constexpr int BH = Bsz * Hn;                  // 16384

typedef __attribute__((ext_vector_type(8))) short short8v;  // 8 bf16
typedef __attribute__((ext_vector_type(4))) float f32x4;
typedef __attribute__((ext_vector_type(8))) int int8v;

__device__ __forceinline__ float sigmoidf_(float x) {
    return 1.0f / (1.0f + expf(-x));
}
__device__ __forceinline__ float sigfast_(float x) {
    return __builtin_amdgcn_rcpf(1.0f + __builtin_amdgcn_exp2f(x * -1.44269504f));
}
__device__ __forceinline__ float bf2f(unsigned short u) {
    return __uint_as_float(((unsigned)u) << 16);
}
__device__ __forceinline__ unsigned short f2bf(float f) {
    unsigned x = __float_as_uint(f);
    return (unsigned short)((x + 0x7fff + ((x >> 16) & 1)) >> 16);  // RNE
}
// OCP e4m3fn encode: HW packed convert if available, else sw RNE
__device__ __forceinline__ unsigned char f2e4m3(float x) {
#if __has_builtin(__builtin_amdgcn_cvt_pk_fp8_f32)
    return (unsigned char)(__builtin_amdgcn_cvt_pk_fp8_f32(x, 0.f, 0, false) & 0xff);
#else
    unsigned b = __float_as_uint(x);
    unsigned s = (b >> 31) << 7;
    b &= 0x7fffffffu;
    unsigned code;
    if (__uint_as_float(b) < 0.015625f) {
        code = (unsigned)__float2int_rn(__uint_as_float(b) * 512.0f);
    } else {
        unsigned r = b + 0x7ffffu + ((b >> 20) & 1);
        int e = (int)(r >> 23) - 127;
        code = (unsigned)(((e + 7) << 3) | ((r >> 20) & 7));
    }
    return (unsigned char)(s | code);
#endif
}
// pack two f32 -> two fp8 bytes (low 16 bits)
__device__ __forceinline__ unsigned short f2e4m3x2(float a, float b) {
#if __has_builtin(__builtin_amdgcn_cvt_pk_fp8_f32)
    return (unsigned short)(__builtin_amdgcn_cvt_pk_fp8_f32(a, b, 0, false) & 0xffff);
#else
    return (unsigned short)(f2e4m3(a) | ((unsigned)f2e4m3(b) << 8));
#endif
}
// fp8 e4m3 byte SEL of dword -> f32 (SEL must be compile-time constant)
template<int SEL>
__device__ __forceinline__ float fp8tof(unsigned d) {
#if __has_builtin(__builtin_amdgcn_cvt_f32_fp8)
    return __builtin_amdgcn_cvt_f32_fp8((int)d, SEL);
#else
    unsigned v = (d >> (8 * SEL)) & 0xff;
    unsigned s = v >> 7, e = (v >> 3) & 15, m = v & 7;
    float r = e ? __uint_as_float(((e + 120) << 23) | (m << 20))
                : (float)m * 0.001953125f;   // 2^-9
    return s ? -r : r;
#endif
}
// fp4 e2m1 encode of x*32 (global scale 2^-5 baked in), nearest on the grid
__device__ __forceinline__ unsigned f4enc(float x) {
    float y = x * 32.0f;
    unsigned s = (__float_as_uint(y) >> 31) << 3;
    float a = fabsf(y);
    unsigned c;
    if      (a < 0.25f) c = 0;
    else if (a < 0.75f) c = 1;
    else if (a < 1.25f) c = 2;
    else if (a < 1.75f) c = 3;
    else if (a < 2.5f)  c = 4;
    else if (a < 3.5f)  c = 5;
    else if (a < 5.0f)  c = 6;
    else                c = 7;
    return s | c;
}
__device__ __forceinline__ void gl_lds16(const void* g, void* l) {
    __builtin_amdgcn_global_load_lds(
        (const __attribute__((address_space(1))) void*)g,
        (__attribute__((address_space(3))) void*)l, 16, 0, 0);
}

// ---------------------------------------------------------------------------
// input [B,T,IN] fp32 -> Abf blocked bf16 [mtile 250][kt 4][kq 8][row 128][e 8]
// ---------------------------------------------------------------------------
__global__ __launch_bounds__(256) void cvt_in(
    const float* __restrict__ in, unsigned short* __restrict__ Abf)
{
    __shared__ float t[128][65];
    const int tid = threadIdx.x;
    const int mtile = blockIdx.x >> 2, kt = blockIdx.x & 3;
    const int rr = tid >> 4, cc = (tid & 15) * 4;
#pragma unroll
    for (int j = 0; j < 8; ++j) {
        int row = j * 16 + rr;
        int m = mtile * 128 + row;
        float4 v = *(const float4*)
            &in[((long)(m & 31) * Tn + (m >> 5)) * INn + kt * 64 + cc];
        t[row][cc] = v.x; t[row][cc + 1] = v.y;
        t[row][cc + 2] = v.z; t[row][cc + 3] = v.w;
    }
    __syncthreads();
    unsigned short* dst = Abf + (long)(mtile * 4 + kt) * 8192;
#pragma unroll
    for (int j = 0; j < 4; ++j) {
        int q = tid + 256 * j;
        int kq = q >> 7, row = q & 127;
        short8v o;
#pragma unroll
        for (int i = 0; i < 8; ++i) o[i] = (short)f2bf(t[row][kq * 8 + i]);
        *(short8v*)&dst[(long)q * 8] = o;
    }
}

// ---------------------------------------------------------------------------
// Weight [K][NG] fp32 -> blocked bf16 B^T tiles [ntile][KT_][kq 8][n 64][e 8]
// ---------------------------------------------------------------------------
template<int KT_, int NG>
__global__ __launch_bounds__(256) void cvt_b(
    const float* __restrict__ Wg, unsigned short* __restrict__ Bb)
{
    int c = blockIdx.x * 256 + threadIdx.x;
    int n = c & 63;
    int c2 = c >> 6;
    int kq = c2 & 7;
    int c3 = c2 >> 3;
    int kt = c3 % KT_, ntile = c3 / KT_;
    short8v o;
#pragma unroll
    for (int i = 0; i < 8; ++i)
        o[i] = (short)f2bf(Wg[(long)(kt * 64 + kq * 8 + i) * NG + ntile * 64 + n]);
    *(short8v*)&Bb[(long)c * 8] = o;
}

// ---------------------------------------------------------------------------
// W_lat [k 512][h 512] fp32 -> Wq4 [h 512][k/2 256] fp4-packed (x32 scale).
// ---------------------------------------------------------------------------
__global__ __launch_bounds__(256) void wlat_cvt4(
    const float* __restrict__ W, unsigned char* __restrict__ Wq4)
{
    __shared__ float tile[64][33];
    const int tid = threadIdx.x;
    const int hx = blockIdx.x & 15, ky = blockIdx.x >> 4;   // 16 x 8
    const int h0 = hx * 32, k0 = ky * 64;
#pragma unroll
    for (int j = 0; j < 8; ++j) {
        int idx = j * 256 + tid;
        int kk = idx >> 5, hh = idx & 31;
        tile[kk][hh] = W[(long)(k0 + kk) * Hn + h0 + hh];
    }
    __syncthreads();
#pragma unroll
    for (int j = 0; j < 4; ++j) {
        int o = j * 256 + tid;
        int hh = o >> 5, kb = o & 31;
        unsigned lo = f4enc(tile[2 * kb][hh]);
        unsigned hi = f4enc(tile[2 * kb + 1][hh]);
        Wq4[(long)(h0 + hh) * 256 + ky * 32 + kb] = (unsigned char)(lo | (hi << 4));
    }
}

// ---------------------------------------------------------------------------
// ph1 bf16 MFMA GEMM: 128x64 tile, BK=64, 256 thr. A blocked.
// C bf16 written with BT map: row m -> SYN[(b*Tn + t)*N]  (b=m&31, t=m>>5)
// ---------------------------------------------------------------------------
template<int KT>
__global__ __launch_bounds__(256) void gemm_ph1(
    const unsigned short* __restrict__ A, const unsigned short* __restrict__ Bm,
    unsigned short* __restrict__ C, int N)
{
    __shared__ unsigned short Asl[2][8192];
    __shared__ unsigned short Bsl[2][4096];

    const int tid = threadIdx.x, lane = tid & 63, w = tid >> 6;
    const int ntile = blockIdx.x, mtile = blockIdx.y;
    const unsigned short* Abase = A + (long)mtile * KT * 8192;
    const unsigned short* Bbase = Bm + (long)ntile * KT * 4096;

    auto stageA = [&](int kt, int buf) {
#pragma unroll
        for (int j = 0; j < 4; ++j) {
            int c = tid + 256 * j;
            gl_lds16(Abase + (long)kt * 8192 + (long)c * 8, &Asl[buf][c * 8]);
        }
    };
    auto stageB = [&](int kt, int buf) {
#pragma unroll
        for (int j = 0; j < 2; ++j) {
            int c = tid + 256 * j;
            gl_lds16(Bbase + (long)kt * 4096 + (long)c * 8, &Bsl[buf][c * 8]);
        }
    };

    f32x4 acc[2][4] = {};
    stageA(0, 0); stageB(0, 0);
    int cur = 0;
#pragma unroll
    for (int kt = 0; kt < KT; ++kt) {
        __syncthreads();
        if (kt + 1 < KT) { stageA(kt + 1, cur ^ 1); stageB(kt + 1, cur ^ 1); }
#pragma unroll
        for (int ks = 0; ks < 2; ++ks) {
            const int kq = ks * 4 + (lane >> 4);
            short8v bfr[4];
#pragma unroll
            for (int nt = 0; nt < 4; ++nt)
                bfr[nt] = *(const short8v*)
                    &Bsl[cur][kq * 512 + (nt * 16 + (lane & 15)) * 8];
#pragma unroll
            for (int mt = 0; mt < 2; ++mt) {
                short8v afr = *(const short8v*)
                    &Asl[cur][kq * 1024 + (w * 32 + mt * 16 + (lane & 15)) * 8];
#pragma unroll
                for (int nt = 0; nt < 4; ++nt)
                    acc[mt][nt] = __builtin_amdgcn_mfma_f32_16x16x32_bf16(
                        afr, bfr[nt], acc[mt][nt], 0, 0, 0);
            }
        }
        cur ^= 1;
    }
#pragma unroll
    for (int mt = 0; mt < 2; ++mt)
#pragma unroll
        for (int r = 0; r < 4; ++r) {
            int row = mtile * 128 + w * 32 + mt * 16 + (lane >> 4) * 4 + r;
            long crow = ((long)(row & 31) * Tn + (row >> 5)) * (long)N;
#pragma unroll
            for (int nt = 0; nt < 4; ++nt) {
                int col = ntile * 64 + nt * 16 + (lane & 15);
                C[crow + col] = f2bf(acc[mt][nt][r]);
            }
        }
}

// ---------------------------------------------------------------------------
// ph3 bf16 MFMA GEMM, A = flat [32000][512] bf16 (F). 128x64 tile, KT=8.
// ---------------------------------------------------------------------------
__global__ __launch_bounds__(256) void gemm_out_flat(
    const unsigned short* __restrict__ Af, const unsigned short* __restrict__ Bm,
    float* __restrict__ C, const float* __restrict__ bias)
{
    constexpr int KT = 8;
    __shared__ unsigned short Asl[2][8192];
    __shared__ unsigned short Bsl[2][4096];

    const int tid = threadIdx.x, lane = tid & 63, w = tid >> 6;
    const int ntile = blockIdx.x, mtile = blockIdx.y;
    const unsigned short* Ab = Af + (long)mtile * 128 * Hn;
    const unsigned short* Bbase = Bm + (long)ntile * KT * 4096;

    auto stageA = [&](int kt, int buf) {
#pragma unroll
        for (int j = 0; j < 4; ++j) {
            int c = tid + 256 * j;
            int row = c >> 3, slot = c & 7;
            int kqs = slot ^ (row & 7);
            gl_lds16(Ab + (long)row * Hn + kt * 64 + kqs * 8,
                     &Asl[buf][c * 8]);
        }
    };
    auto stageB = [&](int kt, int buf) {
#pragma unroll
        for (int j = 0; j < 2; ++j) {
            int c = tid + 256 * j;
            gl_lds16(Bbase + (long)kt * 4096 + (long)c * 8, &Bsl[buf][c * 8]);
        }
    };

    f32x4 acc[2][4] = {};
    stageA(0, 0); stageB(0, 0);
    int cur = 0;
#pragma unroll
    for (int kt = 0; kt < KT; ++kt) {
        __syncthreads();
        if (kt + 1 < KT) { stageA(kt + 1, cur ^ 1); stageB(kt + 1, cur ^ 1); }
#pragma unroll
        for (int ks = 0; ks < 2; ++ks) {
            const int kq = ks * 4 + (lane >> 4);
            short8v bfr[4];
#pragma unroll
            for (int nt = 0; nt < 4; ++nt)
                bfr[nt] = *(const short8v*)
                    &Bsl[cur][kq * 512 + (nt * 16 + (lane & 15)) * 8];
#pragma unroll
            for (int mt = 0; mt < 2; ++mt) {
                int row = w * 32 + mt * 16 + (lane & 15);
                short8v afr = *(const short8v*)((const char*)&Asl[cur][0]
                    + ((unsigned)(row * 128 + kq * 16)
                       ^ ((unsigned)(row & 7) << 4)));
#pragma unroll
                for (int nt = 0; nt < 4; ++nt)
                    acc[mt][nt] = __builtin_amdgcn_mfma_f32_16x16x32_bf16(
                        afr, bfr[nt], acc[mt][nt], 0, 0, 0);
            }
        }
        cur ^= 1;
    }
#pragma unroll
    for (int mt = 0; mt < 2; ++mt)
#pragma unroll
        for (int r = 0; r < 4; ++r) {
            int row = mtile * 128 + w * 32 + mt * 16 + (lane >> 4) * 4 + r;
            long crow = ((long)(row & 31) * Tn + (row >> 5)) * (long)OUTn;
#pragma unroll
            for (int nt = 0; nt < 4; ++nt) {
                int col = ntile * 64 + nt * 16 + (lane & 15);
                C[crow + col] = acc[mt][nt][r] + bias[col];
            }
        }
}

// ---------------------------------------------------------------------------
// Phase 2: 32 blocks (one per batch b), 512 threads (8 waves).
// W fp4 LDS-resident (128 KB). A fp8 DOUBLE-buffered (2x10 KB) -> Sy is
// wave-local -> ONE barrier per stage. Sy fp8 [n][t] (10 KB) via HW cvts.
// mfma_scale 16x16x128 f8f6f4 (A fp8, B fp4, uniform scales, x2^-5 epilogue).
// ---------------------------------------------------------------------------
__global__ __launch_bounds__(512) void phase2_bpart(
    const unsigned char* __restrict__ Wq4,   // [512 n][256 B] fp4 packed
    const unsigned short* __restrict__ SYN,  // [B][T][H] bf16
    unsigned short* __restrict__ Fb,         // [32000][512] bf16 flat
    const float* __restrict__ tkm, const float* __restrict__ thr,
    const float* __restrict__ aamp, const float* __restrict__ tascr,
    const float* __restrict__ tkasc)
{
    __shared__ unsigned char Wl[512 * 256];     // 128 KB fp4, swizzled
    __shared__ unsigned char Afp8[2][20 * 512]; // 2 x 10 KB fp8, swizzled
    __shared__ unsigned char Syq[512 * 20];     // 10 KB fp8 [n][t]

    const int tid = threadIdx.x;
    const int b = blockIdx.x;
    const int lane = tid & 63, w = tid >> 6;

    // ---- stage W fp4 into LDS once (swizzle ^((n&7)<<4) per 16B chunk)
#pragma unroll
    for (int i = 0; i < 16; ++i) {
        int c = i * 512 + tid;                // 16B chunk id, 8192 total
        int n = c >> 4, ci = c & 15;
        int4 v = *(const int4*)(Wq4 + (long)n * 256 + ci * 16);
        *(int4*)(&Wl[(unsigned)(n * 256 + ci * 16) ^ ((unsigned)(n & 7) << 4)]) = v;
    }

    // ---- per-thread ew params: h = tid
    const int h = tid;
    const float dkm  = sigmoidf_(tkm[h]);
    const float th   = thr[h];
    const float am0  = aamp[h],       am1 = aamp[Hn + h];
    const float rr0  = 1.f - 2.f * sigmoidf_(tascr[h]);
    const float rr1  = 1.f - 2.f * sigmoidf_(tascr[Hn + h]);
    const float dk0  = sigmoidf_(tkasc[h]);
    const float dk1  = sigmoidf_(tkasc[Hn + h]);
    const float kR   = dkm * Rc;
    float volt = 0.f, fir = 0.f, a0 = 0.f, a1 = 0.f;

    // frag address invariants
    const int g = lane >> 4;                  // k-group 0..3
    const int r0 = lane & 15, r1 = 16 + (lane & 15);
    const unsigned a0b = (unsigned)(r0 * 512 + g * 32);
    const unsigned a1b = (unsigned)(r1 * 512 + g * 32);
    const unsigned s0 = (unsigned)((r0 & 7) << 4);
    const unsigned s1 = (unsigned)((r1 & 7) << 4);
    unsigned wboff[4], wbswz[4];
#pragma unroll
    for (int nt = 0; nt < 4; ++nt) {
        int n = w * 64 + nt * 16 + (lane & 15);
        wboff[nt] = (unsigned)(n * 256 + g * 16);
        wbswz[nt] = (unsigned)((n & 7) << 4);
    }

    __syncthreads();   // W staged

#pragma unroll 1
    for (int k = 0; k < NBLK; ++k) {
        // ff-syn loads ([b][t][h] layout: step stride 1KB, imm-foldable)
        const unsigned short* synb = SYN + ((long)b * Tn + k * DELAY) * Hn + h;
        float ff[DELAY];
#pragma unroll
        for (int s = 0; s < DELAY; ++s)
            ff[s] = bf2f(synb[s * Hn]);

        if (k > 0) {
            const unsigned char* Ab = &Afp8[k & 1][0];
            f32x4 acc[2][4] = {};
#pragma unroll
            for (int kt = 0; kt < 4; ++kt) {     // K tiles of 128
                int8v va0 = {}, va1 = {};
                {
                    unsigned lo = (a0b + kt * 128) ^ s0;
                    unsigned hi = (a0b + kt * 128 + 16) ^ s0;
                    *(int4*)&va0       = *(const int4*)(Ab + lo);
                    *((int4*)&va0 + 1) = *(const int4*)(Ab + hi);
                    lo = (a1b + kt * 128) ^ s1;
                    hi = (a1b + kt * 128 + 16) ^ s1;
                    *(int4*)&va1       = *(const int4*)(Ab + lo);
                    *((int4*)&va1 + 1) = *(const int4*)(Ab + hi);
                }
#pragma unroll
                for (int nt = 0; nt < 4; ++nt) {
                    int8v vb = {};
                    *(int4*)&vb = *(const int4*)(&Wl[0]
                        + ((wboff[nt] + kt * 64) ^ wbswz[nt]));
                    acc[0][nt] = __builtin_amdgcn_mfma_scale_f32_16x16x128_f8f6f4(
                        va0, vb, acc[0][nt], 0, 4, 0, 127, 0, 127);
                    acc[1][nt] = __builtin_amdgcn_mfma_scale_f32_16x16x128_f8f6f4(
                        va1, vb, acc[1][nt], 0, 4, 0, 127, 0, 127);
                }
            }
            // epilogue -> Syq[n][t] fp8 (x 2^-5 dequant), packed pairs.
            // C frag: col=lane&15, t = mt*16 + (lane>>4)*4 + r
#pragma unroll
            for (int mt = 0; mt < 2; ++mt)
#pragma unroll
                for (int rp = 0; rp < 2; ++rp) {
                    int t = mt * 16 + (lane >> 4) * 4 + rp * 2;
                    if (t < DELAY) {
#pragma unroll
                        for (int nt = 0; nt < 4; ++nt) {
                            int n = w * 64 + nt * 16 + (lane & 15);
                            *(unsigned short*)&Syq[n * 20 + t] =
                                f2e4m3x2(acc[mt][nt][rp * 2]     * 0.03125f,
                                         acc[mt][nt][rp * 2 + 1] * 0.03125f);
                        }
                    }
                }
        }
        // NO barrier here: Syq strip is wave-local (written and read by the
        // same wave); A buffers are disjoint across stages.

        // ---- lateral values: 5 dword LDS reads + HW fp8->f32 cvt
        float latv[DELAY];
        if (k > 0) {
            const unsigned* sp = (const unsigned*)&Syq[h * 20];
#pragma unroll
            for (int j = 0; j < 5; ++j) {
                unsigned d = sp[j];
                latv[4 * j + 0] = fp8tof<0>(d);
                latv[4 * j + 1] = fp8tof<1>(d);
                latv[4 * j + 2] = fp8tof<2>(d);
                latv[4 * j + 3] = fp8tof<3>(d);
            }
        } else {
#pragma unroll
            for (int i = 0; i < DELAY; ++i) latv[i] = 0.f;
        }

        // ---- elementwise recurrence (20 steps); writes A[(k+1)&1] + flat F
        unsigned char* An = &Afp8[(k + 1) & 1][0];
        unsigned short* Fo = Fb + ((long)(k * DELAY * Bsz + b)) * Hn + h;
#pragma unroll
        for (int s = 0; s < DELAY; ++s) {
            float sv = ff[s] + latv[s];
            a0 = a0 * (rr0 * fir * DTc + (1.f - dk0)) + am0 * fir * DTc;
            a1 = a1 * (rr1 * fir * DTc + (1.f - dk1)) + am1 * fir * DTc;
            volt = volt * (1.f - dkm - fir) + kR * (sv + a0 + a1);
            fir = sigfast_(volt - th);
            An[(unsigned)(s * 512 + h) ^ ((unsigned)(s & 7) << 4)] = f2e4m3(fir);
            Fo[(long)s * BH] = f2bf(fir);
        }
        __syncthreads();   // A[(k+1)&1] visible to all waves for next GEMM
    }
}

extern "C" void kernel_launch(void* const* d_in, const int* in_sizes, int n_in,
                              void* d_out, int out_size, void* d_ws, size_t ws_size,
                              hipStream_t stream) {
    const float* input = (const float*)d_in[0];   // [B,T,IN]
    const float* w_iv  = (const float*)d_in[1];   // [IN,H]
    const float* w_lat = (const float*)d_in[2];   // [H,H]
    const float* thr   = (const float*)d_in[3];   // [1,H]
    const float* tkm   = (const float*)d_in[4];   // [1,H]
    const float* aamp  = (const float*)d_in[5];   // [A,1,H]
    const float* tascr = (const float*)d_in[6];   // [A,1,H]
    const float* tkasc = (const float*)d_in[7];   // [A,1,H]
    const float* outw  = (const float*)d_in[8];   // [H,OUT]
    const float* outb  = (const float*)d_in[9];   // [OUT]
    float* out = (float*)d_out;                   // [B,T,OUT]

    const size_t TBH = (size_t)Tn * BH;           // 16,384,000
    unsigned short* SYNb = (unsigned short*)d_ws;         // [B][T][H] bf16
    unsigned short* Fb   = SYNb + TBH;                    // [32000][512] bf16
    unsigned short* Abf  = Fb + TBH;                      // blocked bf16 input
    unsigned char* Wq4   = (unsigned char*)(Abf + (size_t)8192 * 1000);
    unsigned short* Wivb = (unsigned short*)(Wq4 + (size_t)Hn * 256);
    unsigned short* Wowb = Wivb + (size_t)INn * Hn;

    // Phase 0: conversions
    cvt_in<<<1000, 256, 0, stream>>>(input, Abf);
    cvt_b<4, 512><<<64, 256, 0, stream>>>(w_iv, Wivb);
    cvt_b<8, 128><<<32, 256, 0, stream>>>(outw, Wowb);
    wlat_cvt4<<<128, 256, 0, stream>>>(w_lat, Wq4);

    // Phase 1: SYN(bf16, [b][t][h]) = input @ W_iv  (M=32000, N=512, K=256)
    gemm_ph1<4><<<dim3(8, 250), 256, 0, stream>>>(Abf, Wivb, SYNb, Hn);

    // Phase 2: 32 independent per-batch blocks, W fp4 LDS-resident
    phase2_bpart<<<32, 512, 0, stream>>>(Wq4, SYNb, Fb,
                                         tkm, thr, aamp, tascr, tkasc);

    // Phase 3: out = F_flat @ out_w + out_b  (M=32000, N=128, K=512)
    gemm_out_flat<<<dim3(2, 250), 256, 0, stream>>>(Fb, Wowb, out, outb);
}

// Round 19
// 246.585 us; speedup vs baseline: 3.0593x; 1.0049x over previous
//
#include <hip/hip_runtime.h>
#include <math.h>

// GLIFR (BNNFC) : B=32, T=1000, IN=256, H=512, OUT=128, A=2, DELAY=20
//  cvts: input->Abf (blocked bf16), W_iv/out_w -> blocked bf16,
//        W_lat -> Wq4 [h][k] fp4 e2m1 (x32 pre-scale, global scale 2^-5)
//  ph1: SYN(bf16, [b][t][h]) = input @ W_iv   (bf16 MFMA GEMM, BT C-map)
//  ph2: 32 blocks, 512 thr. W fp4 LDS-resident; A fp8 double-buffered;
//       Sy fp8 wave-local; ONE barrier/stage. R19: serial ew loop is pure
//       math (fir in regs); An/Fo stores batched post-loop (off the chain);
//       Fo cvt via v_cvt_pk_bf16_f32 (1 op / 2 values).
//  ph3: out = F_flat @ out_w + out_b    (bf16 MFMA GEMM)

constexpr int Bsz   = 32;
constexpr int Tn    = 1000;
constexpr int INn   = 256;
constexpr int Hn    = 512;
constexpr int OUTn  = 128;
constexpr int DELAY = 20;
constexpr int NBLK  = Tn / DELAY;   // 50
constexpr float DTc = 0.05f;
constexpr float Rc  = 0.1f;
constexpr int BH = Bsz * Hn;                  // 16384

typedef __attribute__((ext_vector_type(8))) short short8v;  // 8 bf16
typedef __attribute__((ext_vector_type(4))) float f32x4;
typedef __attribute__((ext_vector_type(8))) int int8v;

__device__ __forceinline__ float sigmoidf_(float x) {
    return 1.0f / (1.0f + expf(-x));
}
__device__ __forceinline__ float sigfast_(float x) {
    return __builtin_amdgcn_rcpf(1.0f + __builtin_amdgcn_exp2f(x * -1.44269504f));
}
__device__ __forceinline__ float bf2f(unsigned short u) {
    return __uint_as_float(((unsigned)u) << 16);
}
__device__ __forceinline__ unsigned short f2bf(float f) {
    unsigned x = __float_as_uint(f);
    return (unsigned short)((x + 0x7fff + ((x >> 16) & 1)) >> 16);  // RNE
}
// pack two f32 -> one dword of two bf16 (HW, RNE)
__device__ __forceinline__ unsigned cvtpk_bf16(float a, float b) {
    unsigned u;
    asm("v_cvt_pk_bf16_f32 %0, %1, %2" : "=v"(u) : "v"(a), "v"(b));
    return u;
}
// OCP e4m3fn encode: HW packed convert if available, else sw RNE
__device__ __forceinline__ unsigned char f2e4m3(float x) {
#if __has_builtin(__builtin_amdgcn_cvt_pk_fp8_f32)
    return (unsigned char)(__builtin_amdgcn_cvt_pk_fp8_f32(x, 0.f, 0, false) & 0xff);
#else
    unsigned b = __float_as_uint(x);
    unsigned s = (b >> 31) << 7;
    b &= 0x7fffffffu;
    unsigned code;
    if (__uint_as_float(b) < 0.015625f) {
        code = (unsigned)__float2int_rn(__uint_as_float(b) * 512.0f);
    } else {
        unsigned r = b + 0x7ffffu + ((b >> 20) & 1);
        int e = (int)(r >> 23) - 127;
        code = (unsigned)(((e + 7) << 3) | ((r >> 20) & 7));
    }
    return (unsigned char)(s | code);
#endif
}
// pack two f32 -> two fp8 bytes (low 16 bits)
__device__ __forceinline__ unsigned short f2e4m3x2(float a, float b) {
#if __has_builtin(__builtin_amdgcn_cvt_pk_fp8_f32)
    return (unsigned short)(__builtin_amdgcn_cvt_pk_fp8_f32(a, b, 0, false) & 0xffff);
#else
    return (unsigned short)(f2e4m3(a) | ((unsigned)f2e4m3(b) << 8));
#endif
}
// fp8 e4m3 byte SEL of dword -> f32 (SEL must be compile-time constant)
template<int SEL>
__device__ __forceinline__ float fp8tof(unsigned d) {
#if __has_builtin(__builtin_amdgcn_cvt_f32_fp8)
    return __builtin_amdgcn_cvt_f32_fp8((int)d, SEL);
#else
    unsigned v = (d >> (8 * SEL)) & 0xff;
    unsigned s = v >> 7, e = (v >> 3) & 15, m = v & 7;
    float r = e ? __uint_as_float(((e + 120) << 23) | (m << 20))
                : (float)m * 0.001953125f;   // 2^-9
    return s ? -r : r;
#endif
}
// fp4 e2m1 encode of x*32 (global scale 2^-5 baked in), nearest on the grid
__device__ __forceinline__ unsigned f4enc(float x) {
    float y = x * 32.0f;
    unsigned s = (__float_as_uint(y) >> 31) << 3;
    float a = fabsf(y);
    unsigned c;
    if      (a < 0.25f) c = 0;
    else if (a < 0.75f) c = 1;
    else if (a < 1.25f) c = 2;
    else if (a < 1.75f) c = 3;
    else if (a < 2.5f)  c = 4;
    else if (a < 3.5f)  c = 5;
    else if (a < 5.0f)  c = 6;
    else                c = 7;
    return s | c;
}
__device__ __forceinline__ void gl_lds16(const void* g, void* l) {
    __builtin_amdgcn_global_load_lds(
        (const __attribute__((address_space(1))) void*)g,
        (__attribute__((address_space(3))) void*)l, 16, 0, 0);
}

// ---------------------------------------------------------------------------
// input [B,T,IN] fp32 -> Abf blocked bf16 [mtile 250][kt 4][kq 8][row 128][e 8]
// ---------------------------------------------------------------------------
__global__ __launch_bounds__(256) void cvt_in(
    const float* __restrict__ in, unsigned short* __restrict__ Abf)
{
    __shared__ float t[128][65];
    const int tid = threadIdx.x;
    const int mtile = blockIdx.x >> 2, kt = blockIdx.x & 3;
    const int rr = tid >> 4, cc = (tid & 15) * 4;
#pragma unroll
    for (int j = 0; j < 8; ++j) {
        int row = j * 16 + rr;
        int m = mtile * 128 + row;
        float4 v = *(const float4*)
            &in[((long)(m & 31) * Tn + (m >> 5)) * INn + kt * 64 + cc];
        t[row][cc] = v.x; t[row][cc + 1] = v.y;
        t[row][cc + 2] = v.z; t[row][cc + 3] = v.w;
    }
    __syncthreads();
    unsigned short* dst = Abf + (long)(mtile * 4 + kt) * 8192;
#pragma unroll
    for (int j = 0; j < 4; ++j) {
        int q = tid + 256 * j;
        int kq = q >> 7, row = q & 127;
        short8v o;
#pragma unroll
        for (int i = 0; i < 8; ++i) o[i] = (short)f2bf(t[row][kq * 8 + i]);
        *(short8v*)&dst[(long)q * 8] = o;
    }
}

// ---------------------------------------------------------------------------
// Weight [K][NG] fp32 -> blocked bf16 B^T tiles [ntile][KT_][kq 8][n 64][e 8]
// ---------------------------------------------------------------------------
template<int KT_, int NG>
__global__ __launch_bounds__(256) void cvt_b(
    const float* __restrict__ Wg, unsigned short* __restrict__ Bb)
{
    int c = blockIdx.x * 256 + threadIdx.x;
    int n = c & 63;
    int c2 = c >> 6;
    int kq = c2 & 7;
    int c3 = c2 >> 3;
    int kt = c3 % KT_, ntile = c3 / KT_;
    short8v o;
#pragma unroll
    for (int i = 0; i < 8; ++i)
        o[i] = (short)f2bf(Wg[(long)(kt * 64 + kq * 8 + i) * NG + ntile * 64 + n]);
    *(short8v*)&Bb[(long)c * 8] = o;
}

// ---------------------------------------------------------------------------
// W_lat [k 512][h 512] fp32 -> Wq4 [h 512][k/2 256] fp4-packed (x32 scale).
// ---------------------------------------------------------------------------
__global__ __launch_bounds__(256) void wlat_cvt4(
    const float* __restrict__ W, unsigned char* __restrict__ Wq4)
{
    __shared__ float tile[64][33];
    const int tid = threadIdx.x;
    const int hx = blockIdx.x & 15, ky = blockIdx.x >> 4;   // 16 x 8
    const int h0 = hx * 32, k0 = ky * 64;
#pragma unroll
    for (int j = 0; j < 8; ++j) {
        int idx = j * 256 + tid;
        int kk = idx >> 5, hh = idx & 31;
        tile[kk][hh] = W[(long)(k0 + kk) * Hn + h0 + hh];
    }
    __syncthreads();
#pragma unroll
    for (int j = 0; j < 4; ++j) {
        int o = j * 256 + tid;
        int hh = o >> 5, kb = o & 31;
        unsigned lo = f4enc(tile[2 * kb][hh]);
        unsigned hi = f4enc(tile[2 * kb + 1][hh]);
        Wq4[(long)(h0 + hh) * 256 + ky * 32 + kb] = (unsigned char)(lo | (hi << 4));
    }
}

// ---------------------------------------------------------------------------
// ph1 bf16 MFMA GEMM: 128x64 tile, BK=64, 256 thr. A blocked.
// C bf16 written with BT map: row m -> SYN[(b*Tn + t)*N]  (b=m&31, t=m>>5)
// ---------------------------------------------------------------------------
template<int KT>
__global__ __launch_bounds__(256) void gemm_ph1(
    const unsigned short* __restrict__ A, const unsigned short* __restrict__ Bm,
    unsigned short* __restrict__ C, int N)
{
    __shared__ unsigned short Asl[2][8192];
    __shared__ unsigned short Bsl[2][4096];

    const int tid = threadIdx.x, lane = tid & 63, w = tid >> 6;
    const int ntile = blockIdx.x, mtile = blockIdx.y;
    const unsigned short* Abase = A + (long)mtile * KT * 8192;
    const unsigned short* Bbase = Bm + (long)ntile * KT * 4096;

    auto stageA = [&](int kt, int buf) {
#pragma unroll
        for (int j = 0; j < 4; ++j) {
            int c = tid + 256 * j;
            gl_lds16(Abase + (long)kt * 8192 + (long)c * 8, &Asl[buf][c * 8]);
        }
    };
    auto stageB = [&](int kt, int buf) {
#pragma unroll
        for (int j = 0; j < 2; ++j) {
            int c = tid + 256 * j;
            gl_lds16(Bbase + (long)kt * 4096 + (long)c * 8, &Bsl[buf][c * 8]);
        }
    };

    f32x4 acc[2][4] = {};
    stageA(0, 0); stageB(0, 0);
    int cur = 0;
#pragma unroll
    for (int kt = 0; kt < KT; ++kt) {
        __syncthreads();
        if (kt + 1 < KT) { stageA(kt + 1, cur ^ 1); stageB(kt + 1, cur ^ 1); }
#pragma unroll
        for (int ks = 0; ks < 2; ++ks) {
            const int kq = ks * 4 + (lane >> 4);
            short8v bfr[4];
#pragma unroll
            for (int nt = 0; nt < 4; ++nt)
                bfr[nt] = *(const short8v*)
                    &Bsl[cur][kq * 512 + (nt * 16 + (lane & 15)) * 8];
#pragma unroll
            for (int mt = 0; mt < 2; ++mt) {
                short8v afr = *(const short8v*)
                    &Asl[cur][kq * 1024 + (w * 32 + mt * 16 + (lane & 15)) * 8];
#pragma unroll
                for (int nt = 0; nt < 4; ++nt)
                    acc[mt][nt] = __builtin_amdgcn_mfma_f32_16x16x32_bf16(
                        afr, bfr[nt], acc[mt][nt], 0, 0, 0);
            }
        }
        cur ^= 1;
    }
#pragma unroll
    for (int mt = 0; mt < 2; ++mt)
#pragma unroll
        for (int r = 0; r < 4; ++r) {
            int row = mtile * 128 + w * 32 + mt * 16 + (lane >> 4) * 4 + r;
            long crow = ((long)(row & 31) * Tn + (row >> 5)) * (long)N;
#pragma unroll
            for (int nt = 0; nt < 4; ++nt) {
                int col = ntile * 64 + nt * 16 + (lane & 15);
                C[crow + col] = f2bf(acc[mt][nt][r]);
            }
        }
}

// ---------------------------------------------------------------------------
// ph3 bf16 MFMA GEMM, A = flat [32000][512] bf16 (F). 128x64 tile, KT=8.
// ---------------------------------------------------------------------------
__global__ __launch_bounds__(256) void gemm_out_flat(
    const unsigned short* __restrict__ Af, const unsigned short* __restrict__ Bm,
    float* __restrict__ C, const float* __restrict__ bias)
{
    constexpr int KT = 8;
    __shared__ unsigned short Asl[2][8192];
    __shared__ unsigned short Bsl[2][4096];

    const int tid = threadIdx.x, lane = tid & 63, w = tid >> 6;
    const int ntile = blockIdx.x, mtile = blockIdx.y;
    const unsigned short* Ab = Af + (long)mtile * 128 * Hn;
    const unsigned short* Bbase = Bm + (long)ntile * KT * 4096;

    auto stageA = [&](int kt, int buf) {
#pragma unroll
        for (int j = 0; j < 4; ++j) {
            int c = tid + 256 * j;
            int row = c >> 3, slot = c & 7;
            int kqs = slot ^ (row & 7);
            gl_lds16(Ab + (long)row * Hn + kt * 64 + kqs * 8,
                     &Asl[buf][c * 8]);
        }
    };
    auto stageB = [&](int kt, int buf) {
#pragma unroll
        for (int j = 0; j < 2; ++j) {
            int c = tid + 256 * j;
            gl_lds16(Bbase + (long)kt * 4096 + (long)c * 8, &Bsl[buf][c * 8]);
        }
    };

    f32x4 acc[2][4] = {};
    stageA(0, 0); stageB(0, 0);
    int cur = 0;
#pragma unroll
    for (int kt = 0; kt < KT; ++kt) {
        __syncthreads();
        if (kt + 1 < KT) { stageA(kt + 1, cur ^ 1); stageB(kt + 1, cur ^ 1); }
#pragma unroll
        for (int ks = 0; ks < 2; ++ks) {
            const int kq = ks * 4 + (lane >> 4);
            short8v bfr[4];
#pragma unroll
            for (int nt = 0; nt < 4; ++nt)
                bfr[nt] = *(const short8v*)
                    &Bsl[cur][kq * 512 + (nt * 16 + (lane & 15)) * 8];
#pragma unroll
            for (int mt = 0; mt < 2; ++mt) {
                int row = w * 32 + mt * 16 + (lane & 15);
                short8v afr = *(const short8v*)((const char*)&Asl[cur][0]
                    + ((unsigned)(row * 128 + kq * 16)
                       ^ ((unsigned)(row & 7) << 4)));
#pragma unroll
                for (int nt = 0; nt < 4; ++nt)
                    acc[mt][nt] = __builtin_amdgcn_mfma_f32_16x16x32_bf16(
                        afr, bfr[nt], acc[mt][nt], 0, 0, 0);
            }
        }
        cur ^= 1;
    }
#pragma unroll
    for (int mt = 0; mt < 2; ++mt)
#pragma unroll
        for (int r = 0; r < 4; ++r) {
            int row = mtile * 128 + w * 32 + mt * 16 + (lane >> 4) * 4 + r;
            long crow = ((long)(row & 31) * Tn + (row >> 5)) * (long)OUTn;
#pragma unroll
            for (int nt = 0; nt < 4; ++nt) {
                int col = ntile * 64 + nt * 16 + (lane & 15);
                C[crow + col] = acc[mt][nt][r] + bias[col];
            }
        }
}

// ---------------------------------------------------------------------------
// Phase 2: 32 blocks (one per batch b), 512 threads (8 waves).
// W fp4 LDS-resident (128 KB). A fp8 double-buffered (2x10 KB); Sy fp8
// wave-local; ONE barrier/stage. Serial ew loop = pure math (fir in regs);
// stores batched post-loop.
// ---------------------------------------------------------------------------
__global__ __launch_bounds__(512) void phase2_bpart(
    const unsigned char* __restrict__ Wq4,   // [512 n][256 B] fp4 packed
    const unsigned short* __restrict__ SYN,  // [B][T][H] bf16
    unsigned short* __restrict__ Fb,         // [32000][512] bf16 flat
    const float* __restrict__ tkm, const float* __restrict__ thr,
    const float* __restrict__ aamp, const float* __restrict__ tascr,
    const float* __restrict__ tkasc)
{
    __shared__ unsigned char Wl[512 * 256];     // 128 KB fp4, swizzled
    __shared__ unsigned char Afp8[2][20 * 512]; // 2 x 10 KB fp8, swizzled
    __shared__ unsigned char Syq[512 * 20];     // 10 KB fp8 [n][t]

    const int tid = threadIdx.x;
    const int b = blockIdx.x;
    const int lane = tid & 63, w = tid >> 6;

    // ---- stage W fp4 into LDS once (swizzle ^((n&7)<<4) per 16B chunk)
#pragma unroll
    for (int i = 0; i < 16; ++i) {
        int c = i * 512 + tid;                // 16B chunk id, 8192 total
        int n = c >> 4, ci = c & 15;
        int4 v = *(const int4*)(Wq4 + (long)n * 256 + ci * 16);
        *(int4*)(&Wl[(unsigned)(n * 256 + ci * 16) ^ ((unsigned)(n & 7) << 4)]) = v;
    }

    // ---- per-thread ew params: h = tid
    const int h = tid;
    const float dkm  = sigmoidf_(tkm[h]);
    const float th   = thr[h];
    const float am0  = aamp[h],       am1 = aamp[Hn + h];
    const float rr0  = 1.f - 2.f * sigmoidf_(tascr[h]);
    const float rr1  = 1.f - 2.f * sigmoidf_(tascr[Hn + h]);
    const float dk0  = sigmoidf_(tkasc[h]);
    const float dk1  = sigmoidf_(tkasc[Hn + h]);
    const float kR   = dkm * Rc;
    float volt = 0.f, fir = 0.f, a0 = 0.f, a1 = 0.f;

    // frag address invariants
    const int g = lane >> 4;                  // k-group 0..3
    const int r0 = lane & 15, r1 = 16 + (lane & 15);
    const unsigned a0b = (unsigned)(r0 * 512 + g * 32);
    const unsigned a1b = (unsigned)(r1 * 512 + g * 32);
    const unsigned s0 = (unsigned)((r0 & 7) << 4);
    const unsigned s1 = (unsigned)((r1 & 7) << 4);
    unsigned wboff[4], wbswz[4];
#pragma unroll
    for (int nt = 0; nt < 4; ++nt) {
        int n = w * 64 + nt * 16 + (lane & 15);
        wboff[nt] = (unsigned)(n * 256 + g * 16);
        wbswz[nt] = (unsigned)((n & 7) << 4);
    }

    __syncthreads();   // W staged

#pragma unroll 1
    for (int k = 0; k < NBLK; ++k) {
        // ff-syn loads ([b][t][h] layout: step stride 1KB, imm-foldable)
        const unsigned short* synb = SYN + ((long)b * Tn + k * DELAY) * Hn + h;
        float ff[DELAY];
#pragma unroll
        for (int s = 0; s < DELAY; ++s)
            ff[s] = bf2f(synb[s * Hn]);

        if (k > 0) {
            const unsigned char* Ab = &Afp8[k & 1][0];
            f32x4 acc[2][4] = {};
#pragma unroll
            for (int kt = 0; kt < 4; ++kt) {     // K tiles of 128
                int8v va0 = {}, va1 = {};
                {
                    unsigned lo = (a0b + kt * 128) ^ s0;
                    unsigned hi = (a0b + kt * 128 + 16) ^ s0;
                    *(int4*)&va0       = *(const int4*)(Ab + lo);
                    *((int4*)&va0 + 1) = *(const int4*)(Ab + hi);
                    lo = (a1b + kt * 128) ^ s1;
                    hi = (a1b + kt * 128 + 16) ^ s1;
                    *(int4*)&va1       = *(const int4*)(Ab + lo);
                    *((int4*)&va1 + 1) = *(const int4*)(Ab + hi);
                }
#pragma unroll
                for (int nt = 0; nt < 4; ++nt) {
                    int8v vb = {};
                    *(int4*)&vb = *(const int4*)(&Wl[0]
                        + ((wboff[nt] + kt * 64) ^ wbswz[nt]));
                    acc[0][nt] = __builtin_amdgcn_mfma_scale_f32_16x16x128_f8f6f4(
                        va0, vb, acc[0][nt], 0, 4, 0, 127, 0, 127);
                    acc[1][nt] = __builtin_amdgcn_mfma_scale_f32_16x16x128_f8f6f4(
                        va1, vb, acc[1][nt], 0, 4, 0, 127, 0, 127);
                }
            }
            // epilogue -> Syq[n][t] fp8 (x 2^-5 dequant), packed pairs.
#pragma unroll
            for (int mt = 0; mt < 2; ++mt)
#pragma unroll
                for (int rp = 0; rp < 2; ++rp) {
                    int t = mt * 16 + (lane >> 4) * 4 + rp * 2;
                    if (t < DELAY) {
#pragma unroll
                        for (int nt = 0; nt < 4; ++nt) {
                            int n = w * 64 + nt * 16 + (lane & 15);
                            *(unsigned short*)&Syq[n * 20 + t] =
                                f2e4m3x2(acc[mt][nt][rp * 2]     * 0.03125f,
                                         acc[mt][nt][rp * 2 + 1] * 0.03125f);
                        }
                    }
                }
        }
        // NO barrier: Syq strip is wave-local; A buffers disjoint across stages.

        // ---- lateral values: 5 dword LDS reads + HW fp8->f32 cvt
        float latv[DELAY];
        if (k > 0) {
            const unsigned* sp = (const unsigned*)&Syq[h * 20];
#pragma unroll
            for (int j = 0; j < 5; ++j) {
                unsigned d = sp[j];
                latv[4 * j + 0] = fp8tof<0>(d);
                latv[4 * j + 1] = fp8tof<1>(d);
                latv[4 * j + 2] = fp8tof<2>(d);
                latv[4 * j + 3] = fp8tof<3>(d);
            }
        } else {
#pragma unroll
            for (int i = 0; i < DELAY; ++i) latv[i] = 0.f;
        }

        // ---- serial recurrence: PURE MATH, fir values kept in registers
        float fv[DELAY];
#pragma unroll
        for (int s = 0; s < DELAY; ++s) {
            float sv = ff[s] + latv[s];
            a0 = a0 * (rr0 * fir * DTc + (1.f - dk0)) + am0 * fir * DTc;
            a1 = a1 * (rr1 * fir * DTc + (1.f - dk1)) + am1 * fir * DTc;
            volt = volt * (1.f - dkm - fir) + kR * (sv + a0 + a1);
            fir = sigfast_(volt - th);
            fv[s] = fir;
        }

        // ---- batched stores (off the serial chain)
        unsigned char* An = &Afp8[(k + 1) & 1][0];
#pragma unroll
        for (int s = 0; s < DELAY; s += 2) {
            unsigned short pk = f2e4m3x2(fv[s], fv[s + 1]);
            An[(unsigned)(s * 512 + h) ^ ((unsigned)(s & 7) << 4)]
                = (unsigned char)(pk & 0xff);
            An[(unsigned)((s + 1) * 512 + h) ^ ((unsigned)((s + 1) & 7) << 4)]
                = (unsigned char)(pk >> 8);
        }
        unsigned short* Fo = Fb + ((long)(k * DELAY * Bsz + b)) * Hn + h;
#pragma unroll
        for (int s = 0; s < DELAY; s += 2) {
            unsigned u = cvtpk_bf16(fv[s], fv[s + 1]);
            Fo[(long)s * BH]       = (unsigned short)(u & 0xffff);
            Fo[(long)(s + 1) * BH] = (unsigned short)(u >> 16);
        }
        __syncthreads();   // A[(k+1)&1] visible to all waves for next GEMM
    }
}

extern "C" void kernel_launch(void* const* d_in, const int* in_sizes, int n_in,
                              void* d_out, int out_size, void* d_ws, size_t ws_size,
                              hipStream_t stream) {
    const float* input = (const float*)d_in[0];   // [B,T,IN]
    const float* w_iv  = (const float*)d_in[1];   // [IN,H]
    const float* w_lat = (const float*)d_in[2];   // [H,H]
    const float* thr   = (const float*)d_in[3];   // [1,H]
    const float* tkm   = (const float*)d_in[4];   // [1,H]
    const float* aamp  = (const float*)d_in[5];   // [A,1,H]
    const float* tascr = (const float*)d_in[6];   // [A,1,H]
    const float* tkasc = (const float*)d_in[7];   // [A,1,H]
    const float* outw  = (const float*)d_in[8];   // [H,OUT]
    const float* outb  = (const float*)d_in[9];   // [OUT]
    float* out = (float*)d_out;                   // [B,T,OUT]

    const size_t TBH = (size_t)Tn * BH;           // 16,384,000
    unsigned short* SYNb = (unsigned short*)d_ws;         // [B][T][H] bf16
    unsigned short* Fb   = SYNb + TBH;                    // [32000][512] bf16
    unsigned short* Abf  = Fb + TBH;                      // blocked bf16 input
    unsigned char* Wq4   = (unsigned char*)(Abf + (size_t)8192 * 1000);
    unsigned short* Wivb = (unsigned short*)(Wq4 + (size_t)Hn * 256);
    unsigned short* Wowb = Wivb + (size_t)INn * Hn;

    // Phase 0: conversions
    cvt_in<<<1000, 256, 0, stream>>>(input, Abf);
    cvt_b<4, 512><<<64, 256, 0, stream>>>(w_iv, Wivb);
    cvt_b<8, 128><<<32, 256, 0, stream>>>(outw, Wowb);
    wlat_cvt4<<<128, 256, 0, stream>>>(w_lat, Wq4);

    // Phase 1: SYN(bf16, [b][t][h]) = input @ W_iv  (M=32000, N=512, K=256)
    gemm_ph1<4><<<dim3(8, 250), 256, 0, stream>>>(Abf, Wivb, SYNb, Hn);

    // Phase 2: 32 independent per-batch blocks, W fp4 LDS-resident
    phase2_bpart<<<32, 512, 0, stream>>>(Wq4, SYNb, Fb,
                                         tkm, thr, aamp, tascr, tkasc);

    // Phase 3: out = F_flat @ out_w + out_b  (M=32000, N=128, K=512)
    gemm_out_flat<<<dim3(2, 250), 256, 0, stream>>>(Fb, Wowb, out, outb);
}